// Round 5
// baseline (443.432 us; speedup 1.0000x reference)
//
#include <hip/hip_runtime.h>
#include <hip/hip_bf16.h>
#include <math.h>

typedef __bf16 bf16_t;
typedef __bf16 bf16x8 __attribute__((ext_vector_type(8)));
typedef float f32x4 __attribute__((ext_vector_type(4)));

#define T_DIM 2048
#define C_DIM 2048
#define NH 16
#define HS 128
#define NLQ 1536
#define NLKV 512
#define DHR 64
#define QKD 192  // HS + DHR

// ---------------------------------------------------------------- dtype detect
__global__ void detect_k(const bf16_t* __restrict__ x, int* __restrict__ flag) {
  int bad = 0;
  for (int i = threadIdx.x; i < 256; i += 64) {
    float v = (float)x[i];
    if (!(fabsf(v) < 1.0e6f)) bad = 1;  // catches NaN too
  }
  unsigned long long m = __ballot(bad);
  if (threadIdx.x == 0) *flag = (m != 0ull) ? 1 : 0;
}

// ---------------------------------------------------------------- batched convert
struct CvPack {
  const void* src[9];
  bf16_t* dst[9];
  int n[9];
};

__global__ __launch_bounds__(256) void convert_all_k(CvPack p, const int* __restrict__ flag) {
  const int which = blockIdx.y;
  const int n = p.n[which];
  const int f32 = *flag;
  const int stride = gridDim.x * 256 * 8;
  for (int i = (blockIdx.x * 256 + threadIdx.x) * 8; i < n; i += stride) {
    if (f32) {
      const float* s = (const float*)p.src[which] + i;
      f32x4 lo = *(const f32x4*)s;
      f32x4 hi = *(const f32x4*)(s + 4);
      bf16x8 v;
#pragma unroll
      for (int j = 0; j < 4; ++j) { v[j] = (bf16_t)lo[j]; v[j + 4] = (bf16_t)hi[j]; }
      *(bf16x8*)(p.dst[which] + i) = v;
    } else {
      *(bf16x8*)(p.dst[which] + i) = *(const bf16x8*)((const bf16_t*)p.src[which] + i);
    }
  }
}

// ---------------------------------------------------------------- transpose (dtype-flex in)
__global__ void transpose_k(const void* __restrict__ in, bf16_t* __restrict__ out,
                            int R, int C, const int* __restrict__ flag) {
  __shared__ bf16_t tile[32][33];
  const int f32 = *flag;
  int bx = blockIdx.x * 32, by = blockIdx.y * 32;
  int tx = threadIdx.x, ty = threadIdx.y;
  for (int i = ty; i < 32; i += 8) {
    int r = by + i, c = bx + tx;
    if (r < R && c < C) {
      size_t idx = (size_t)r * C + c;
      tile[i][tx] = f32 ? (bf16_t)((const float*)in)[idx] : ((const bf16_t*)in)[idx];
    }
  }
  __syncthreads();
  for (int i = ty; i < 32; i += 8) {
    int r = bx + i, c = by + tx;  // out[r][c] = in[c][r]
    if (r < C && c < R) out[(size_t)r * R + c] = tile[tx][i];
  }
}

// ---------------------------------------------------------------- async global->LDS (16B)
__device__ __forceinline__ void async16(const bf16_t* g, bf16_t* l) {
  __builtin_amdgcn_global_load_lds(
      (const __attribute__((address_space(1))) void*)g,
      (__attribute__((address_space(3))) void*)l, 16, 0, 0);
}

// ---------------------------------------------------------------- GEMM  C = A @ B^T (bf16)
// m97-structure: BK=32, unpadded LDS, global_load_lds dwordx4 staging.
#define BM 128
#define BN 128

__global__ __launch_bounds__(256) void gemm_nt(const bf16_t* __restrict__ A,
                                               const bf16_t* __restrict__ B,
                                               bf16_t* __restrict__ Cm,
                                               int M, int N, int K,
                                               int lda, int ldb, int ldc) {
  __shared__ bf16_t As[BM * 32];  // 8 KB
  __shared__ bf16_t Bs[BN * 32];  // 8 KB
  const int tid = threadIdx.x;
  const int lane = tid & 63;
  const int wave = tid >> 6;
  const int l16 = lane & 15, quad = lane >> 4;
  const int bm = blockIdx.x * BM, bn = blockIdx.y * BN;
  const int wm = (wave >> 1) * 64, wn = (wave & 1) * 64;
  // staging: lane covers row (lane>>2) within a 16-row group, col (lane&3)*8
  const int srow = lane >> 2;
  const int scol = (lane & 3) * 8;
  f32x4 acc[4][4] = {};

  for (int k0 = 0; k0 < K; k0 += 32) {
    __syncthreads();  // previous tile's MFMA reads done
#pragma unroll
    for (int pss = 0; pss < 2; ++pss) {
      int rowT = pss * 64 + wave * 16 + srow;
      int ar = bm + rowT; if (ar > M - 1) ar = M - 1;
      async16(A + (size_t)ar * lda + k0 + scol, As + (pss * 64 + wave * 16) * 32);
      int br = bn + rowT; if (br > N - 1) br = N - 1;
      async16(B + (size_t)br * ldb + k0 + scol, Bs + (pss * 64 + wave * 16) * 32);
    }
    __syncthreads();  // drains vmcnt -> LDS ready
    bf16x8 af[4], bfr[4];
#pragma unroll
    for (int i = 0; i < 4; ++i)
      af[i] = *(const bf16x8*)(As + (wm + i * 16 + l16) * 32 + quad * 8);
#pragma unroll
    for (int j = 0; j < 4; ++j)
      bfr[j] = *(const bf16x8*)(Bs + (wn + j * 16 + l16) * 32 + quad * 8);
#pragma unroll
    for (int i = 0; i < 4; ++i)
#pragma unroll
      for (int j = 0; j < 4; ++j)
        acc[i][j] = __builtin_amdgcn_mfma_f32_16x16x32_bf16(af[i], bfr[j], acc[i][j], 0, 0, 0);
  }
#pragma unroll
  for (int i = 0; i < 4; ++i)
#pragma unroll
    for (int j = 0; j < 4; ++j)
#pragma unroll
      for (int r = 0; r < 4; ++r) {
        int gm = bm + wm + i * 16 + quad * 4 + r;
        int gn = bn + wn + j * 16 + l16;
        if (gm < M && gn < N) Cm[(size_t)gm * ldc + gn] = (bf16_t)acc[i][j][r];
      }
}

// ---------------------------------------------------------------- pack + rope
// qcat: (T, 3072) = [q_up (cols 0..2047) | q_r (cols 2048..3071)]
__global__ void pack_q_k(const bf16_t* __restrict__ qcat,
                         const bf16_t* __restrict__ fc, const bf16_t* __restrict__ fs,
                         bf16_t* __restrict__ Qp) {
  int idx = blockIdx.x * blockDim.x + threadIdx.x;
  if (idx >= NH * T_DIM * 96) return;
  int j = idx % 96;
  int t = (idx / 96) % T_DIM;
  int h = idx / (96 * T_DIM);
  const float scale = 0.07216878364870323f;  // 1/sqrt(HS+DHR)
  bf16_t* out = Qp + ((size_t)h * T_DIM + t) * QKD;
  if (j < 64) {
    float a = (float)qcat[(size_t)t * 3072 + h * HS + 2 * j];
    float b = (float)qcat[(size_t)t * 3072 + h * HS + 2 * j + 1];
    out[2 * j] = (bf16_t)(a * scale);
    out[2 * j + 1] = (bf16_t)(b * scale);
  } else {
    int i = j - 64;
    float re = (float)qcat[(size_t)t * 3072 + 2048 + h * DHR + 2 * i];
    float im = (float)qcat[(size_t)t * 3072 + 2048 + h * DHR + 2 * i + 1];
    float c = (float)fc[t * 32 + i], s = (float)fs[t * 32 + i];
    out[HS + 2 * i] = (bf16_t)((re * c - im * s) * scale);
    out[HS + 2 * i + 1] = (bf16_t)((re * s + im * c) * scale);
  }
}

// khead: (T, 2048); k_r lives in xa cols 2048..2111 (ld 2112)
__global__ void pack_k_k(const bf16_t* __restrict__ khead, const bf16_t* __restrict__ xa,
                         const bf16_t* __restrict__ fc, const bf16_t* __restrict__ fs,
                         bf16_t* __restrict__ Kp) {
  int idx = blockIdx.x * blockDim.x + threadIdx.x;
  if (idx >= NH * T_DIM * 96) return;
  int j = idx % 96;
  int t = (idx / 96) % T_DIM;
  int h = idx / (96 * T_DIM);
  bf16_t* out = Kp + ((size_t)h * T_DIM + t) * QKD;
  if (j < 64) {
    out[2 * j] = khead[(size_t)t * C_DIM + h * HS + 2 * j];
    out[2 * j + 1] = khead[(size_t)t * C_DIM + h * HS + 2 * j + 1];
  } else {
    int i = j - 64;
    float re = (float)xa[(size_t)t * 2112 + 2048 + 2 * i];
    float im = (float)xa[(size_t)t * 2112 + 2048 + 2 * i + 1];
    float c = (float)fc[t * 32 + i], s = (float)fs[t * 32 + i];
    out[HS + 2 * i] = (bf16_t)(re * c - im * s);
    out[HS + 2 * i + 1] = (bf16_t)(re * s + im * c);
  }
}

// ---------------------------------------------------------------- flash attention (KV-split)
// blockIdx.x = p in [0,48): p<32 -> qtile=16+(p>>1), chunk=p&1, partial out;
//                           p>=32 -> qtile=47-p, full range, direct Y out.
#define FBM 64
#define FBN 64
#define KPITCH 200
#define VPITCH 72
#define PPITCH 72

__global__ __launch_bounds__(256) void flash_k(const bf16_t* __restrict__ Qp,
                                               const bf16_t* __restrict__ Kp,
                                               const bf16_t* __restrict__ VT,
                                               void* __restrict__ Y,
                                               const int* __restrict__ flag,
                                               float* __restrict__ Opart,
                                               float* __restrict__ Mpart,
                                               float* __restrict__ Lpart) {
  __shared__ bf16_t Ksm[FBN * KPITCH];
  __shared__ bf16_t Vtsm[HS * VPITCH];
  __shared__ bf16_t Psm[4][16 * PPITCH];
  const int tid = threadIdx.x;
  const int lane = tid & 63, wave = tid >> 6;
  const int l16 = lane & 15, quad = lane >> 4;
  const int h = blockIdx.y;
  const int p = blockIdx.x;
  int qtile, kt0, kt1, partial;
  if (p < 32) { qtile = 16 + (p >> 1); kt0 = (p & 1) * 16; kt1 = (p & 1) ? (qtile + 1) : 16; partial = 1; }
  else        { qtile = 47 - p;        kt0 = 0;            kt1 = qtile + 1;                 partial = 0; }
  const int qb = qtile * FBM;
  const int f32out = *flag;

  bf16x8 aq[6];
  const bf16_t* qbase = Qp + ((size_t)h * T_DIM + qb + wave * 16 + l16) * QKD;
#pragma unroll
  for (int c = 0; c < 6; ++c) aq[c] = *(const bf16x8*)(qbase + c * 32 + quad * 8);

  f32x4 o[8] = {};
  float m_i[4], l_i[4];
#pragma unroll
  for (int r = 0; r < 4; ++r) { m_i[r] = -3.0e38f; l_i[r] = 0.f; }

  const bf16_t* kg_base = Kp + (size_t)h * T_DIM * QKD;
  const bf16_t* vg_base = VT + (size_t)(h * HS) * T_DIM;

  // register prefetch (load kt+1 during compute of kt)
  bf16x8 kreg[6], vreg[4];
  {
    const bf16_t* kg = kg_base + (size_t)kt0 * FBN * QKD;
#pragma unroll
    for (int i = 0; i < 6; ++i) {
      int idx = i * 256 + tid, row = idx / 24, c8 = idx % 24;
      kreg[i] = *(const bf16x8*)(kg + (size_t)row * QKD + c8 * 8);
    }
    const bf16_t* vg = vg_base + kt0 * FBN;
#pragma unroll
    for (int i = 0; i < 4; ++i) {
      int idx = i * 256 + tid, row = idx >> 3, c8 = idx & 7;
      vreg[i] = *(const bf16x8*)(vg + (size_t)row * T_DIM + c8 * 8);
    }
  }

  for (int kt = kt0; kt < kt1; ++kt) {
    __syncthreads();  // previous compute done -> LDS writable
#pragma unroll
    for (int i = 0; i < 6; ++i) {
      int idx = i * 256 + tid, row = idx / 24, c8 = idx % 24;
      *(bf16x8*)(Ksm + row * KPITCH + c8 * 8) = kreg[i];
    }
#pragma unroll
    for (int i = 0; i < 4; ++i) {
      int idx = i * 256 + tid, row = idx >> 3, c8 = idx & 7;
      *(bf16x8*)(Vtsm + row * VPITCH + c8 * 8) = vreg[i];
    }
    __syncthreads();  // LDS ready
    if (kt + 1 < kt1) {
      const bf16_t* kg = kg_base + (size_t)(kt + 1) * FBN * QKD;
#pragma unroll
      for (int i = 0; i < 6; ++i) {
        int idx = i * 256 + tid, row = idx / 24, c8 = idx % 24;
        kreg[i] = *(const bf16x8*)(kg + (size_t)row * QKD + c8 * 8);
      }
      const bf16_t* vg = vg_base + (kt + 1) * FBN;
#pragma unroll
      for (int i = 0; i < 4; ++i) {
        int idx = i * 256 + tid, row = idx >> 3, c8 = idx & 7;
        vreg[i] = *(const bf16x8*)(vg + (size_t)row * T_DIM + c8 * 8);
      }
    }
    // S = Q @ K^T
    f32x4 sc[4] = {};
#pragma unroll
    for (int nt = 0; nt < 4; ++nt)
#pragma unroll
      for (int c = 0; c < 6; ++c) {
        bf16x8 bk = *(const bf16x8*)(Ksm + (nt * 16 + l16) * KPITCH + c * 32 + quad * 8);
        sc[nt] = __builtin_amdgcn_mfma_f32_16x16x32_bf16(aq[c], bk, sc[nt], 0, 0, 0);
      }
    if (kt == qtile) {
#pragma unroll
      for (int nt = 0; nt < 4; ++nt) {
        int s_loc = nt * 16 + l16;
#pragma unroll
        for (int r = 0; r < 4; ++r) {
          int t_loc = wave * 16 + quad * 4 + r;
          if (s_loc > t_loc) sc[nt][r] = -3.0e38f;
        }
      }
    }
    // online softmax
    float pv_[4][4];
#pragma unroll
    for (int r = 0; r < 4; ++r) {
      float mx = fmaxf(fmaxf(sc[0][r], sc[1][r]), fmaxf(sc[2][r], sc[3][r]));
#pragma unroll
      for (int m = 1; m < 16; m <<= 1) mx = fmaxf(mx, __shfl_xor(mx, m, 64));
      float mn = fmaxf(m_i[r], mx);
      float alpha = exp2f((m_i[r] - mn) * 1.4426950408889634f);
      float rs = 0.f;
#pragma unroll
      for (int nt = 0; nt < 4; ++nt) {
        float pv = exp2f((sc[nt][r] - mn) * 1.4426950408889634f);
        pv_[nt][r] = pv;
        rs += pv;
      }
#pragma unroll
      for (int m = 1; m < 16; m <<= 1) rs += __shfl_xor(rs, m, 64);
      l_i[r] = l_i[r] * alpha + rs;
      m_i[r] = mn;
#pragma unroll
      for (int dt = 0; dt < 8; ++dt) o[dt][r] *= alpha;
    }
    // P: C-layout -> LDS -> A-operand layout (per-wave buffer, no barrier)
#pragma unroll
    for (int nt = 0; nt < 4; ++nt)
#pragma unroll
      for (int r = 0; r < 4; ++r)
        Psm[wave][(quad * 4 + r) * PPITCH + nt * 16 + l16] = (bf16_t)pv_[nt][r];
#pragma unroll
    for (int s2 = 0; s2 < 2; ++s2) {
      bf16x8 ap = *(const bf16x8*)(&Psm[wave][l16 * PPITCH + s2 * 32 + quad * 8]);
#pragma unroll
      for (int dt = 0; dt < 8; ++dt) {
        bf16x8 bv = *(const bf16x8*)(Vtsm + (dt * 16 + l16) * VPITCH + s2 * 32 + quad * 8);
        o[dt] = __builtin_amdgcn_mfma_f32_16x16x32_bf16(ap, bv, o[dt], 0, 0, 0);
      }
    }
  }

  if (!partial) {
#pragma unroll
    for (int r = 0; r < 4; ++r) {
      float inv = 1.0f / l_i[r];
      int t = qb + wave * 16 + quad * 4 + r;
#pragma unroll
      for (int dt = 0; dt < 8; ++dt) {
        size_t oi = (size_t)t * C_DIM + h * HS + dt * 16 + l16;
        float val = o[dt][r] * inv;
        if (f32out) ((float*)Y)[oi] = val;
        else        ((bf16_t*)Y)[oi] = (bf16_t)val;
      }
    }
  } else {
    const int pi = h * 32 + p;  // p < 32 here
#pragma unroll
    for (int r = 0; r < 4; ++r) {
      int rowl = wave * 16 + quad * 4 + r;
      float* ob = Opart + ((size_t)pi * 64 + rowl) * 128;
#pragma unroll
      for (int dt = 0; dt < 8; ++dt) ob[dt * 16 + l16] = o[dt][r];
      if (l16 == 0) {
        Mpart[(size_t)pi * 64 + rowl] = m_i[r];
        Lpart[(size_t)pi * 64 + rowl] = l_i[r];
      }
    }
  }
}

// ---------------------------------------------------------------- combine partials (qtile>=16)
__global__ __launch_bounds__(256) void combine_k(const float* __restrict__ Opart,
                                                 const float* __restrict__ Mpart,
                                                 const float* __restrict__ Lpart,
                                                 void* __restrict__ Y,
                                                 const int* __restrict__ flag) {
  const int h = blockIdx.y;
  const int qt = blockIdx.x;          // 0..15 -> qtile 16+qt
  const int p0 = h * 32 + qt * 2, p1 = p0 + 1;
  const int row = threadIdx.x >> 2;   // 0..63
  const int c0 = (threadIdx.x & 3) * 32;
  const int f32out = *flag;
  float m0 = Mpart[(size_t)p0 * 64 + row], m1 = Mpart[(size_t)p1 * 64 + row];
  float l0 = Lpart[(size_t)p0 * 64 + row], l1 = Lpart[(size_t)p1 * 64 + row];
  float ms = fmaxf(m0, m1);
  float w0 = exp2f((m0 - ms) * 1.4426950408889634f);
  float w1 = exp2f((m1 - ms) * 1.4426950408889634f);
  float inv = 1.0f / (l0 * w0 + l1 * w1);
  const float* O0 = Opart + ((size_t)p0 * 64 + row) * 128 + c0;
  const float* O1 = Opart + ((size_t)p1 * 64 + row) * 128 + c0;
  int t = (16 + qt) * 64 + row;
  size_t ob = (size_t)t * C_DIM + h * HS + c0;
#pragma unroll
  for (int d4 = 0; d4 < 32; d4 += 4) {
    f32x4 a = *(const f32x4*)(O0 + d4);
    f32x4 b = *(const f32x4*)(O1 + d4);
#pragma unroll
    for (int j = 0; j < 4; ++j) {
      float v = (a[j] * w0 + b[j] * w1) * inv;
      if (f32out) ((float*)Y)[ob + d4 + j] = v;
      else        ((bf16_t*)Y)[ob + d4 + j] = (bf16_t)v;
    }
  }
}

// ---------------------------------------------------------------- launch
extern "C" void kernel_launch(void* const* d_in, const int* in_sizes, int n_in,
                              void* d_out, int out_size, void* d_ws, size_t ws_size,
                              hipStream_t stream) {
  bf16_t* w = (bf16_t*)d_ws;
  int* flag = (int*)d_ws;  // first 4 bytes; buffers start at element 64

  if (ws_size < (size_t)34472000 * 2 + 128) return;

  // ---- workspace layout (bf16 elements), lifetime-aliased ----
  bf16_t* fcc    = w + 64;        // 65536
  bf16_t* fsc    = w + 65600;     // 65536
  bf16_t* xc     = w + 131136;    // 4194304
  bf16_t* BigB   = w + 4325440;   // 4325376 = [W_dq(1536) | W_dkv(512) | W_kr(64)] x 2048
  bf16_t* dqc    = BigB;
  bf16_t* dkvc   = BigB + 3145728;
  bf16_t* krc    = BigB + 4194304;
  bf16_t* Bq     = w + 8650816;   // 4718592 = [W_uq_t(2048) | W_qr(1024)] x 1536
  bf16_t* W_uq_t = Bq;
  bf16_t* qrc    = Bq + 3145728;
  bf16_t* xa     = w + 13369408;  // 4325376: cols [c_q(1536) | c_kv(512) | k_r(64)], ld 2112
  bf16_t* qcat   = w + 17694784;  // 6291456: cols [q_up(2048) | q_r(1024)], ld 3072
  bf16_t* k_head = w + 23986240;  // 4194304
  bf16_t* vhatT  = w + 28180544;  // 4194304
  bf16_t* ukc    = w + 32374848;  // 1048576
  bf16_t* Pt     = w + 33423424;  // 1048576
  // aliases (lifetime-disjoint, verified by launch order below)
  bf16_t* woc    = qcat;          // W_o bf16; dead before qcat GEMM writes here
  bf16_t* W_uv_t = k_head;        // dead before k_head GEMM writes here
  bf16_t* Qpack  = xc;            // 131136..6422592; xc+BigB dead after xa GEMM
  bf16_t* Kpack  = qcat;          // qcat dead after pack_q_k
  // flash partials (f32) over Bq+xa region (dead once packs are done)
  float* Opart = (float*)(w + 6422592);   // 512*64*128 f32 = 16.8 MB -> ends 14811200 (bf16 elems)
  float* Mpart = (float*)(w + 14811200);  // 32768 f32
  float* Lpart = (float*)(w + 14876736);  // 32768 f32 -> ends 14942272 < 17694784 ✓

  detect_k<<<1, 64, 0, stream>>>((const bf16_t*)d_in[0], flag);

  CvPack cp;
  const void* srcs[9] = {d_in[1], d_in[2], d_in[0], d_in[3], d_in[5], d_in[9], d_in[8], d_in[6], d_in[10]};
  bf16_t* dsts[9]     = {fcc,     fsc,     xc,      dqc,     dkvc,    krc,     qrc,     ukc,     woc};
  int ns[9] = {T_DIM * 32, T_DIM * 32, T_DIM * C_DIM, NLQ * C_DIM, NLKV * C_DIM,
               DHR * C_DIM, NH * DHR * NLQ, C_DIM * NLKV, C_DIM * C_DIM};
  for (int i = 0; i < 9; ++i) { cp.src[i] = srcs[i]; cp.dst[i] = dsts[i]; cp.n[i] = ns[i]; }
  convert_all_k<<<dim3(512, 9), 256, 0, stream>>>(cp, flag);

  dim3 tb(32, 8);
  transpose_k<<<dim3(64, 48), tb, 0, stream>>>(d_in[4], W_uq_t, 1536, 2048, flag);
  transpose_k<<<dim3(16, 64), tb, 0, stream>>>(d_in[7], W_uv_t, 2048, 512, flag);

  // Pt = W_o @ W_uv            (2048,512,K=2048)
  gemm_nt<<<dim3(16, 4), 256, 0, stream>>>(woc, W_uv_t, Pt, 2048, 512, 2048, 2048, 2048, 512);
  // xa = x @ [W_dq;W_dkv;W_kr]^T   (2048,2112,K=2048)
  gemm_nt<<<dim3(16, 17), 256, 0, stream>>>(xc, BigB, xa, 2048, 2112, 2048, 2048, 2048, 2112);
  // qcat = c_q @ [W_uq_t;W_qr]^T   (2048,3072,K=1536)
  gemm_nt<<<dim3(16, 24), 256, 0, stream>>>(xa, Bq, qcat, 2048, 3072, 1536, 2112, 1536, 3072);
  // k_head = c_kv @ W_uk^T     (2048,2048,K=512)
  gemm_nt<<<dim3(16, 16), 256, 0, stream>>>(xa + 1536, ukc, k_head, 2048, 2048, 512, 2112, 512, 2048);
  // vhatT = Pt @ c_kv^T        (2048,2048,K=512)
  gemm_nt<<<dim3(16, 16), 256, 0, stream>>>(Pt, xa + 1536, vhatT, 2048, 2048, 512, 512, 2112, 2048);

  int pk = (NH * T_DIM * 96 + 255) / 256;
  pack_q_k<<<pk, 256, 0, stream>>>(qcat, fcc, fsc, Qpack);
  pack_k_k<<<pk, 256, 0, stream>>>(k_head, xa, fcc, fsc, Kpack);

  flash_k<<<dim3(48, NH), 256, 0, stream>>>(Qpack, Kpack, vhatT, d_out, flag, Opart, Mpart, Lpart);
  combine_k<<<dim3(16, NH), 256, 0, stream>>>(Opart, Mpart, Lpart, d_out, flag);
}

// Round 6
// 378.245 us; speedup vs baseline: 1.1723x; 1.1723x over previous
//
#include <hip/hip_runtime.h>
#include <hip/hip_bf16.h>
#include <math.h>

typedef __bf16 bf16_t;
typedef __bf16 bf16x8 __attribute__((ext_vector_type(8)));
typedef float f32x4 __attribute__((ext_vector_type(4)));

#define T_DIM 2048
#define C_DIM 2048
#define NH 16
#define HS 128
#define NLQ 1536
#define NLKV 512
#define DHR 64
#define QKD 192  // HS + DHR

// ---------------------------------------------------------------- dtype detect
__global__ void detect_k(const bf16_t* __restrict__ x, int* __restrict__ flag) {
  int bad = 0;
  for (int i = threadIdx.x; i < 256; i += 64) {
    float v = (float)x[i];
    if (!(fabsf(v) < 1.0e6f)) bad = 1;  // catches NaN too
  }
  unsigned long long m = __ballot(bad);
  if (threadIdx.x == 0) *flag = (m != 0ull) ? 1 : 0;
}

// ---------------------------------------------------------------- batched convert
struct CvPack {
  const void* src[9];
  bf16_t* dst[9];
  int n[9];
};

__global__ __launch_bounds__(256) void convert_all_k(CvPack p, const int* __restrict__ flag) {
  const int which = blockIdx.y;
  const int n = p.n[which];
  const int f32 = *flag;
  const int stride = gridDim.x * 256 * 8;
  for (int i = (blockIdx.x * 256 + threadIdx.x) * 8; i < n; i += stride) {
    if (f32) {
      const float* s = (const float*)p.src[which] + i;
      f32x4 lo = *(const f32x4*)s;
      f32x4 hi = *(const f32x4*)(s + 4);
      bf16x8 v;
#pragma unroll
      for (int j = 0; j < 4; ++j) { v[j] = (bf16_t)lo[j]; v[j + 4] = (bf16_t)hi[j]; }
      *(bf16x8*)(p.dst[which] + i) = v;
    } else {
      *(bf16x8*)(p.dst[which] + i) = *(const bf16x8*)((const bf16_t*)p.src[which] + i);
    }
  }
}

// ---------------------------------------------------------------- transpose (dtype-flex in)
__global__ void transpose_k(const void* __restrict__ in, bf16_t* __restrict__ out,
                            int R, int C, const int* __restrict__ flag) {
  __shared__ bf16_t tile[32][33];
  const int f32 = *flag;
  int bx = blockIdx.x * 32, by = blockIdx.y * 32;
  int tx = threadIdx.x, ty = threadIdx.y;
  for (int i = ty; i < 32; i += 8) {
    int r = by + i, c = bx + tx;
    if (r < R && c < C) {
      size_t idx = (size_t)r * C + c;
      tile[i][tx] = f32 ? (bf16_t)((const float*)in)[idx] : ((const bf16_t*)in)[idx];
    }
  }
  __syncthreads();
  for (int i = ty; i < 32; i += 8) {
    int r = bx + i, c = by + tx;  // out[r][c] = in[c][r]
    if (r < C && c < R) out[(size_t)r * R + c] = tile[tx][i];
  }
}

// ---------------------------------------------------------------- async global->LDS (16B)
__device__ __forceinline__ void async16(const bf16_t* g, bf16_t* l) {
  __builtin_amdgcn_global_load_lds(
      (const __attribute__((address_space(1))) void*)g,
      (__attribute__((address_space(3))) void*)l, 16, 0, 0);
}

// ---------------------------------------------------------------- grouped GEMM  C = A @ B^T
// m97-structure: BK=32, unpadded LDS (row stride 32 elem = 16 dw -> 2-way conflict = free),
// global_load_lds dwordx4 staging. Up to 3 independent GEMMs per launch.
#define BM 128
#define BN 128

struct GDesc {
  const bf16_t* A; const bf16_t* B; bf16_t* C;
  int M, N, K, lda, ldb, ldc, mb, bx0;
};
struct GGrp { GDesc d[3]; };

__global__ __launch_bounds__(256) void gemm_group(GGrp g, int nseg) {
  int bx = blockIdx.x;
  int s = 0;
  while (s + 1 < nseg && bx >= g.d[s + 1].bx0) ++s;
  const GDesc D = g.d[s];
  const int local = bx - D.bx0;
  const int bm = (local % D.mb) * BM, bn = (local / D.mb) * BN;

  __shared__ bf16_t As[BM * 32];  // 8 KB
  __shared__ bf16_t Bs[BN * 32];  // 8 KB
  const int tid = threadIdx.x;
  const int lane = tid & 63;
  const int wave = tid >> 6;
  const int l16 = lane & 15, quad = lane >> 4;
  const int wm = (wave >> 1) * 64, wn = (wave & 1) * 64;
  const int srow = lane >> 2;
  const int scol = (lane & 3) * 8;
  f32x4 acc[4][4] = {};

  for (int k0 = 0; k0 < D.K; k0 += 32) {
    __syncthreads();
#pragma unroll
    for (int pss = 0; pss < 2; ++pss) {
      int rowT = pss * 64 + wave * 16 + srow;
      int ar = bm + rowT; if (ar > D.M - 1) ar = D.M - 1;
      async16(D.A + (size_t)ar * D.lda + k0 + scol, As + (pss * 64 + wave * 16) * 32);
      int br = bn + rowT; if (br > D.N - 1) br = D.N - 1;
      async16(D.B + (size_t)br * D.ldb + k0 + scol, Bs + (pss * 64 + wave * 16) * 32);
    }
    __syncthreads();
    bf16x8 af[4], bfr[4];
#pragma unroll
    for (int i = 0; i < 4; ++i)
      af[i] = *(const bf16x8*)(As + (wm + i * 16 + l16) * 32 + quad * 8);
#pragma unroll
    for (int j = 0; j < 4; ++j)
      bfr[j] = *(const bf16x8*)(Bs + (wn + j * 16 + l16) * 32 + quad * 8);
#pragma unroll
    for (int i = 0; i < 4; ++i)
#pragma unroll
      for (int j = 0; j < 4; ++j)
        acc[i][j] = __builtin_amdgcn_mfma_f32_16x16x32_bf16(af[i], bfr[j], acc[i][j], 0, 0, 0);
  }
#pragma unroll
  for (int i = 0; i < 4; ++i)
#pragma unroll
    for (int j = 0; j < 4; ++j)
#pragma unroll
      for (int r = 0; r < 4; ++r) {
        int gm = bm + wm + i * 16 + quad * 4 + r;
        int gn = bn + wn + j * 16 + l16;
        if (gm < D.M && gn < D.N) D.C[(size_t)gm * D.ldc + gn] = (bf16_t)acc[i][j][r];
      }
}

// ---------------------------------------------------------------- fused pack + rope
// y==0: Q path (qcat -> Qp, scaled);  y==1: K path (khead + xa k_r -> Kp)
__global__ void pack_qk_k(const bf16_t* __restrict__ qcat, const bf16_t* __restrict__ khead,
                          const bf16_t* __restrict__ xa,
                          const bf16_t* __restrict__ fc, const bf16_t* __restrict__ fs,
                          bf16_t* __restrict__ Qp, bf16_t* __restrict__ Kp) {
  int idx = blockIdx.x * blockDim.x + threadIdx.x;
  if (idx >= NH * T_DIM * 96) return;
  int j = idx % 96;
  int t = (idx / 96) % T_DIM;
  int h = idx / (96 * T_DIM);
  if (blockIdx.y == 0) {
    const float scale = 0.07216878364870323f;  // 1/sqrt(HS+DHR)
    bf16_t* out = Qp + ((size_t)h * T_DIM + t) * QKD;
    if (j < 64) {
      float a = (float)qcat[(size_t)t * 3072 + h * HS + 2 * j];
      float b = (float)qcat[(size_t)t * 3072 + h * HS + 2 * j + 1];
      out[2 * j] = (bf16_t)(a * scale);
      out[2 * j + 1] = (bf16_t)(b * scale);
    } else {
      int i = j - 64;
      float re = (float)qcat[(size_t)t * 3072 + 2048 + h * DHR + 2 * i];
      float im = (float)qcat[(size_t)t * 3072 + 2048 + h * DHR + 2 * i + 1];
      float c = (float)fc[t * 32 + i], s = (float)fs[t * 32 + i];
      out[HS + 2 * i] = (bf16_t)((re * c - im * s) * scale);
      out[HS + 2 * i + 1] = (bf16_t)((re * s + im * c) * scale);
    }
  } else {
    bf16_t* out = Kp + ((size_t)h * T_DIM + t) * QKD;
    if (j < 64) {
      out[2 * j] = khead[(size_t)t * C_DIM + h * HS + 2 * j];
      out[2 * j + 1] = khead[(size_t)t * C_DIM + h * HS + 2 * j + 1];
    } else {
      int i = j - 64;
      float re = (float)xa[(size_t)t * 2112 + 2048 + 2 * i];
      float im = (float)xa[(size_t)t * 2112 + 2048 + 2 * i + 1];
      float c = (float)fc[t * 32 + i], s = (float)fs[t * 32 + i];
      out[HS + 2 * i] = (bf16_t)(re * c - im * s);
      out[HS + 2 * i + 1] = (bf16_t)(re * s + im * c);
    }
  }
}

// ---------------------------------------------------------------- flash attention
// FBM=128 (8 waves), FBN=64, KV-split. blockIdx.x = p in [0,24):
//   p<16  : qt = 8+(p>>1), chunk=p&1 (kt [0,qt+1) or [qt+1,2qt+2)), partial out
//   p>=16 : qt = 23-p (7..0), full range, direct Y out
#define FBM 128
#define FBN 64
#define KPITCH 200
#define VPITCH 72
#define PPITCH 72

__global__ __launch_bounds__(512) void flash_k(const bf16_t* __restrict__ Qp,
                                               const bf16_t* __restrict__ Kp,
                                               const bf16_t* __restrict__ VT,
                                               void* __restrict__ Y,
                                               const int* __restrict__ flag,
                                               float* __restrict__ Opart,
                                               float* __restrict__ Mpart,
                                               float* __restrict__ Lpart) {
  __shared__ bf16_t Ksm[FBN * KPITCH];    // 25.6 KB
  __shared__ bf16_t Vtsm[HS * VPITCH];    // 18.4 KB
  __shared__ bf16_t Psm[8][16 * PPITCH];  // 18.4 KB
  const int tid = threadIdx.x;
  const int lane = tid & 63, wave = tid >> 6;  // wave 0..7
  const int l16 = lane & 15, quad = lane >> 4;
  const int h = blockIdx.y;
  const int p = blockIdx.x;
  int qt, kt0, kt1, partial;
  if (p < 16) {
    qt = 8 + (p >> 1);
    int half = qt + 1;
    kt0 = (p & 1) ? half : 0;
    kt1 = (p & 1) ? (2 * qt + 2) : half;
    partial = 1;
  } else {
    qt = 23 - p; kt0 = 0; kt1 = 2 * qt + 2; partial = 0;
  }
  const int qb = qt * FBM;
  const int f32out = *flag;

  bf16x8 aq[6];
  const bf16_t* qbase = Qp + ((size_t)h * T_DIM + qb + wave * 16 + l16) * QKD;
#pragma unroll
  for (int c = 0; c < 6; ++c) aq[c] = *(const bf16x8*)(qbase + c * 32 + quad * 8);

  f32x4 o[8] = {};
  float m_i[4], l_i[4];
#pragma unroll
  for (int r = 0; r < 4; ++r) { m_i[r] = -3.0e38f; l_i[r] = 0.f; }

  const bf16_t* kg_base = Kp + (size_t)h * T_DIM * QKD;
  const bf16_t* vg_base = VT + (size_t)(h * HS) * T_DIM;

  // register prefetch (load kt+1 during compute of kt)
  bf16x8 kreg[3], vreg[2];
  {
    const bf16_t* kg = kg_base + (size_t)kt0 * FBN * QKD;
#pragma unroll
    for (int i = 0; i < 3; ++i) {
      int idx = i * 512 + tid, row = idx / 24, c8 = idx % 24;
      kreg[i] = *(const bf16x8*)(kg + (size_t)row * QKD + c8 * 8);
    }
    const bf16_t* vg = vg_base + kt0 * FBN;
#pragma unroll
    for (int i = 0; i < 2; ++i) {
      int idx = i * 512 + tid, row = idx >> 3, c8 = idx & 7;
      vreg[i] = *(const bf16x8*)(vg + (size_t)row * T_DIM + c8 * 8);
    }
  }

  for (int kt = kt0; kt < kt1; ++kt) {
    __syncthreads();  // previous compute done -> LDS writable
#pragma unroll
    for (int i = 0; i < 3; ++i) {
      int idx = i * 512 + tid, row = idx / 24, c8 = idx % 24;
      *(bf16x8*)(Ksm + row * KPITCH + c8 * 8) = kreg[i];
    }
#pragma unroll
    for (int i = 0; i < 2; ++i) {
      int idx = i * 512 + tid, row = idx >> 3, c8 = idx & 7;
      *(bf16x8*)(Vtsm + row * VPITCH + c8 * 8) = vreg[i];
    }
    __syncthreads();  // LDS ready
    if (kt + 1 < kt1) {
      const bf16_t* kg = kg_base + (size_t)(kt + 1) * FBN * QKD;
#pragma unroll
      for (int i = 0; i < 3; ++i) {
        int idx = i * 512 + tid, row = idx / 24, c8 = idx % 24;
        kreg[i] = *(const bf16x8*)(kg + (size_t)row * QKD + c8 * 8);
      }
      const bf16_t* vg = vg_base + (kt + 1) * FBN;
#pragma unroll
      for (int i = 0; i < 2; ++i) {
        int idx = i * 512 + tid, row = idx >> 3, c8 = idx & 7;
        vreg[i] = *(const bf16x8*)(vg + (size_t)row * T_DIM + c8 * 8);
      }
    }
    // S = Q @ K^T   (this wave's 16 rows x 64 cols)
    f32x4 sc[4] = {};
#pragma unroll
    for (int nt = 0; nt < 4; ++nt)
#pragma unroll
      for (int c = 0; c < 6; ++c) {
        bf16x8 bk = *(const bf16x8*)(Ksm + (nt * 16 + l16) * KPITCH + c * 32 + quad * 8);
        sc[nt] = __builtin_amdgcn_mfma_f32_16x16x32_bf16(aq[c], bk, sc[nt], 0, 0, 0);
      }
    if (kt >= 2 * qt) {  // diagonal region: global causal mask
#pragma unroll
      for (int nt = 0; nt < 4; ++nt) {
        int s_glob = kt * FBN + nt * 16 + l16;
#pragma unroll
        for (int r = 0; r < 4; ++r) {
          int t_glob = qb + wave * 16 + quad * 4 + r;
          if (s_glob > t_glob) sc[nt][r] = -3.0e38f;
        }
      }
    }
    // online softmax
    float pv_[4][4];
#pragma unroll
    for (int r = 0; r < 4; ++r) {
      float mx = fmaxf(fmaxf(sc[0][r], sc[1][r]), fmaxf(sc[2][r], sc[3][r]));
#pragma unroll
      for (int m = 1; m < 16; m <<= 1) mx = fmaxf(mx, __shfl_xor(mx, m, 64));
      float mn = fmaxf(m_i[r], mx);
      float alpha = exp2f((m_i[r] - mn) * 1.4426950408889634f);
      float rs = 0.f;
#pragma unroll
      for (int nt = 0; nt < 4; ++nt) {
        float pv = exp2f((sc[nt][r] - mn) * 1.4426950408889634f);
        pv_[nt][r] = pv;
        rs += pv;
      }
#pragma unroll
      for (int m = 1; m < 16; m <<= 1) rs += __shfl_xor(rs, m, 64);
      l_i[r] = l_i[r] * alpha + rs;
      m_i[r] = mn;
#pragma unroll
      for (int dt = 0; dt < 8; ++dt) o[dt][r] *= alpha;
    }
    // P: C-layout -> LDS -> A-operand layout (per-wave buffer, no extra barrier)
#pragma unroll
    for (int nt = 0; nt < 4; ++nt)
#pragma unroll
      for (int r = 0; r < 4; ++r)
        Psm[wave][(quad * 4 + r) * PPITCH + nt * 16 + l16] = (bf16_t)pv_[nt][r];
#pragma unroll
    for (int s2 = 0; s2 < 2; ++s2) {
      bf16x8 ap = *(const bf16x8*)(&Psm[wave][l16 * PPITCH + s2 * 32 + quad * 8]);
#pragma unroll
      for (int dt = 0; dt < 8; ++dt) {
        bf16x8 bv = *(const bf16x8*)(Vtsm + (dt * 16 + l16) * VPITCH + s2 * 32 + quad * 8);
        o[dt] = __builtin_amdgcn_mfma_f32_16x16x32_bf16(ap, bv, o[dt], 0, 0, 0);
      }
    }
  }

  if (!partial) {
#pragma unroll
    for (int r = 0; r < 4; ++r) {
      float inv = 1.0f / l_i[r];
      int t = qb + wave * 16 + quad * 4 + r;
#pragma unroll
      for (int dt = 0; dt < 8; ++dt) {
        size_t oi = (size_t)t * C_DIM + h * HS + dt * 16 + l16;
        float val = o[dt][r] * inv;
        if (f32out) ((float*)Y)[oi] = val;
        else        ((bf16_t*)Y)[oi] = (bf16_t)val;
      }
    }
  } else {
    const int pi = h * 16 + p;  // p < 16
#pragma unroll
    for (int r = 0; r < 4; ++r) {
      int rowl = wave * 16 + quad * 4 + r;  // 0..127
      float* ob = Opart + ((size_t)pi * 128 + rowl) * 128;
#pragma unroll
      for (int dt = 0; dt < 8; ++dt) ob[dt * 16 + l16] = o[dt][r];
      if (l16 == 0) {
        Mpart[(size_t)pi * 128 + rowl] = m_i[r];
        Lpart[(size_t)pi * 128 + rowl] = l_i[r];
      }
    }
  }
}

// ---------------------------------------------------------------- combine partials (qt>=8)
__global__ __launch_bounds__(256) void combine_k(const float* __restrict__ Opart,
                                                 const float* __restrict__ Mpart,
                                                 const float* __restrict__ Lpart,
                                                 void* __restrict__ Y,
                                                 const int* __restrict__ flag) {
  const int h = blockIdx.y;
  const int qi = blockIdx.x;           // 0..7 -> qt = 8+qi
  const int pi0 = h * 16 + qi * 2, pi1 = pi0 + 1;
  const int row = threadIdx.x >> 1;    // 0..127
  const int c0 = (threadIdx.x & 1) * 64;
  const int f32out = *flag;
  float m0 = Mpart[(size_t)pi0 * 128 + row], m1 = Mpart[(size_t)pi1 * 128 + row];
  float l0 = Lpart[(size_t)pi0 * 128 + row], l1 = Lpart[(size_t)pi1 * 128 + row];
  float ms = fmaxf(m0, m1);
  float w0 = exp2f((m0 - ms) * 1.4426950408889634f);
  float w1 = exp2f((m1 - ms) * 1.4426950408889634f);
  float inv = 1.0f / (l0 * w0 + l1 * w1);
  const float* O0 = Opart + ((size_t)pi0 * 128 + row) * 128 + c0;
  const float* O1 = Opart + ((size_t)pi1 * 128 + row) * 128 + c0;
  int t = (8 + qi) * 128 + row;
  size_t ob = (size_t)t * C_DIM + h * HS + c0;
#pragma unroll
  for (int d4 = 0; d4 < 64; d4 += 4) {
    f32x4 a = *(const f32x4*)(O0 + d4);
    f32x4 b = *(const f32x4*)(O1 + d4);
#pragma unroll
    for (int j = 0; j < 4; ++j) {
      float v = (a[j] * w0 + b[j] * w1) * inv;
      if (f32out) ((float*)Y)[ob + d4 + j] = v;
      else        ((bf16_t*)Y)[ob + d4 + j] = (bf16_t)v;
    }
  }
}

// ---------------------------------------------------------------- launch
extern "C" void kernel_launch(void* const* d_in, const int* in_sizes, int n_in,
                              void* d_out, int out_size, void* d_ws, size_t ws_size,
                              hipStream_t stream) {
  bf16_t* w = (bf16_t*)d_ws;
  int* flag = (int*)d_ws;  // first 4 bytes; buffers start at element 64

  if (ws_size < (size_t)34472000 * 2 + 128) return;

  // ---- workspace layout (bf16 elements), lifetime-aliased ----
  bf16_t* fcc    = w + 64;        // 65536
  bf16_t* fsc    = w + 65600;     // 65536
  bf16_t* xc     = w + 131136;    // 4194304
  bf16_t* BigB   = w + 4325440;   // 4325376 = [W_dq(1536) | W_dkv(512) | W_kr(64)] x 2048
  bf16_t* dqc    = BigB;
  bf16_t* dkvc   = BigB + 3145728;
  bf16_t* krc    = BigB + 4194304;
  bf16_t* Bq     = w + 8650816;   // 4718592 = [W_uq_t(2048) | W_qr(1024)] x 1536
  bf16_t* W_uq_t = Bq;
  bf16_t* qrc    = Bq + 3145728;
  bf16_t* xa     = w + 13369408;  // 4325376: cols [c_q(1536) | c_kv(512) | k_r(64)], ld 2112
  bf16_t* qcat   = w + 17694784;  // 6291456: cols [q_up(2048) | q_r(1024)], ld 3072
  bf16_t* k_head = w + 23986240;  // 4194304
  bf16_t* vhatT  = w + 28180544;  // 4194304
  bf16_t* ukc    = w + 32374848;  // 1048576
  bf16_t* Pt     = w + 33423424;  // 1048576
  // aliases (lifetime-disjoint, verified by launch order below)
  bf16_t* woc    = qcat;          // W_o bf16; dead before qcat GEMM writes here
  bf16_t* W_uv_t = k_head;        // dead before k_head GEMM writes here
  bf16_t* Qpack  = xc;            // xc+BigB dead after xa GEMM
  bf16_t* Kpack  = qcat;          // qcat dead after pack
  // flash partials (f32) over Bq+xa region (dead once pack is done)
  float* Opart = (float*)(w + 6422592);   // 256*128*128 f32 = 16.8 MB -> ends elem 14811200
  float* Mpart = (float*)(w + 14811200);  // 32768 f32
  float* Lpart = (float*)(w + 14876736);  // 32768 f32 -> ends 14942272 < 17694784 (Kpack) OK

  detect_k<<<1, 64, 0, stream>>>((const bf16_t*)d_in[0], flag);

  CvPack cp;
  const void* srcs[9] = {d_in[1], d_in[2], d_in[0], d_in[3], d_in[5], d_in[9], d_in[8], d_in[6], d_in[10]};
  bf16_t* dsts[9]     = {fcc,     fsc,     xc,      dqc,     dkvc,    krc,     qrc,     ukc,     woc};
  int ns[9] = {T_DIM * 32, T_DIM * 32, T_DIM * C_DIM, NLQ * C_DIM, NLKV * C_DIM,
               DHR * C_DIM, NH * DHR * NLQ, C_DIM * NLKV, C_DIM * C_DIM};
  for (int i = 0; i < 9; ++i) { cp.src[i] = srcs[i]; cp.dst[i] = dsts[i]; cp.n[i] = ns[i]; }
  convert_all_k<<<dim3(512, 9), 256, 0, stream>>>(cp, flag);

  dim3 tb(32, 8);
  transpose_k<<<dim3(64, 48), tb, 0, stream>>>(d_in[4], W_uq_t, 1536, 2048, flag);
  transpose_k<<<dim3(16, 64), tb, 0, stream>>>(d_in[7], W_uv_t, 2048, 512, flag);

  // G1: xa = x @ [W_dq;W_dkv;W_kr]^T (272 blk)  ||  Pt = W_o @ W_uv (64 blk)
  {
    GGrp g;
    g.d[0] = {xc,  BigB,   xa, 2048, 2112, 2048, 2048, 2048, 2112, 16, 0};
    g.d[1] = {woc, W_uv_t, Pt, 2048,  512, 2048, 2048, 2048,  512, 16, 272};
    gemm_group<<<336, 256, 0, stream>>>(g, 2);
  }
  // G2: qcat (384 blk) || k_head (256 blk) || vhatT (256 blk)
  {
    GGrp g;
    g.d[0] = {xa,        Bq,        qcat,   2048, 3072, 1536, 2112, 1536, 3072, 16, 0};
    g.d[1] = {xa + 1536, ukc,       k_head, 2048, 2048,  512, 2112,  512, 2048, 16, 384};
    g.d[2] = {Pt,        xa + 1536, vhatT,  2048, 2048,  512,  512, 2112, 2048, 16, 640};
    gemm_group<<<896, 256, 0, stream>>>(g, 3);
  }

  int pk = (NH * T_DIM * 96 + 255) / 256;
  pack_qk_k<<<dim3(pk, 2), 256, 0, stream>>>(qcat, k_head, xa, fcc, fsc, Qpack, Kpack);

  flash_k<<<dim3(24, NH), 512, 0, stream>>>(Qpack, Kpack, vhatT, d_out, flag, Opart, Mpart, Lpart);
  combine_k<<<dim3(8, NH), 256, 0, stream>>>(Opart, Mpart, Lpart, d_out, flag);
}

// Round 7
// 364.184 us; speedup vs baseline: 1.2176x; 1.0386x over previous
//
#include <hip/hip_runtime.h>
#include <hip/hip_bf16.h>
#include <math.h>

typedef __bf16 bf16_t;
typedef __bf16 bf16x4 __attribute__((ext_vector_type(4)));
typedef __bf16 bf16x8 __attribute__((ext_vector_type(8)));
typedef float f32x4 __attribute__((ext_vector_type(4)));

#define T_DIM 2048
#define C_DIM 2048
#define NH 16
#define HS 128
#define NLQ 1536
#define NLKV 512
#define DHR 64
#define QKD 192  // HS + DHR

// ---------------------------------------------------------------- dtype detect
__global__ void detect_k(const bf16_t* __restrict__ x, int* __restrict__ flag) {
  int bad = 0;
  for (int i = threadIdx.x; i < 256; i += 64) {
    float v = (float)x[i];
    if (!(fabsf(v) < 1.0e6f)) bad = 1;  // catches NaN too
  }
  unsigned long long m = __ballot(bad);
  if (threadIdx.x == 0) *flag = (m != 0ull) ? 1 : 0;
}

// ---------------------------------------------------------------- batched convert
struct CvPack {
  const void* src[9];
  bf16_t* dst[9];
  int n[9];
};

__global__ __launch_bounds__(256) void convert_all_k(CvPack p, const int* __restrict__ flag) {
  const int which = blockIdx.y;
  const int n = p.n[which];
  const int f32 = *flag;
  const int stride = gridDim.x * 256 * 8;
  for (int i = (blockIdx.x * 256 + threadIdx.x) * 8; i < n; i += stride) {
    if (f32) {
      const float* s = (const float*)p.src[which] + i;
      f32x4 lo = *(const f32x4*)s;
      f32x4 hi = *(const f32x4*)(s + 4);
      bf16x8 v;
#pragma unroll
      for (int j = 0; j < 4; ++j) { v[j] = (bf16_t)lo[j]; v[j + 4] = (bf16_t)hi[j]; }
      *(bf16x8*)(p.dst[which] + i) = v;
    } else {
      *(bf16x8*)(p.dst[which] + i) = *(const bf16x8*)((const bf16_t*)p.src[which] + i);
    }
  }
}

// ---------------------------------------------------------------- transpose (dtype-flex in)
__global__ void transpose_k(const void* __restrict__ in, bf16_t* __restrict__ out,
                            int R, int C, const int* __restrict__ flag) {
  __shared__ bf16_t tile[32][33];
  const int f32 = *flag;
  int bx = blockIdx.x * 32, by = blockIdx.y * 32;
  int tx = threadIdx.x, ty = threadIdx.y;
  for (int i = ty; i < 32; i += 8) {
    int r = by + i, c = bx + tx;
    if (r < R && c < C) {
      size_t idx = (size_t)r * C + c;
      tile[i][tx] = f32 ? (bf16_t)((const float*)in)[idx] : ((const bf16_t*)in)[idx];
    }
  }
  __syncthreads();
  for (int i = ty; i < 32; i += 8) {
    int r = bx + i, c = by + tx;  // out[r][c] = in[c][r]
    if (r < C && c < R) out[(size_t)r * R + c] = tile[tx][i];
  }
}

// ---------------------------------------------------------------- async global->LDS (16B)
__device__ __forceinline__ void async16(const bf16_t* g, bf16_t* l) {
  __builtin_amdgcn_global_load_lds(
      (const __attribute__((address_space(1))) void*)g,
      (__attribute__((address_space(3))) void*)l, 16, 0, 0);
}

// ---------------------------------------------------------------- grouped GEMM  C = A @ B^T
#define BM 128
#define BN 128

struct GDesc {
  const bf16_t* A; const bf16_t* B; bf16_t* C;
  int M, N, K, lda, ldb, ldc, mb, bx0;
};
struct GGrp { GDesc d[3]; };

__global__ __launch_bounds__(256) void gemm_group(GGrp g, int nseg) {
  int bx = blockIdx.x;
  int s = 0;
  while (s + 1 < nseg && bx >= g.d[s + 1].bx0) ++s;
  const GDesc D = g.d[s];
  const int local = bx - D.bx0;
  const int bm = (local % D.mb) * BM, bn = (local / D.mb) * BN;

  __shared__ bf16_t As[BM * 32];  // 8 KB
  __shared__ bf16_t Bs[BN * 32];  // 8 KB
  const int tid = threadIdx.x;
  const int lane = tid & 63;
  const int wave = tid >> 6;
  const int l16 = lane & 15, quad = lane >> 4;
  const int wm = (wave >> 1) * 64, wn = (wave & 1) * 64;
  const int srow = lane >> 2;
  const int scol = (lane & 3) * 8;
  f32x4 acc[4][4] = {};

  for (int k0 = 0; k0 < D.K; k0 += 32) {
    __syncthreads();
#pragma unroll
    for (int pss = 0; pss < 2; ++pss) {
      int rowT = pss * 64 + wave * 16 + srow;
      int ar = bm + rowT; if (ar > D.M - 1) ar = D.M - 1;
      async16(D.A + (size_t)ar * D.lda + k0 + scol, As + (pss * 64 + wave * 16) * 32);
      int br = bn + rowT; if (br > D.N - 1) br = D.N - 1;
      async16(D.B + (size_t)br * D.ldb + k0 + scol, Bs + (pss * 64 + wave * 16) * 32);
    }
    __syncthreads();
    bf16x8 af[4], bfr[4];
#pragma unroll
    for (int i = 0; i < 4; ++i)
      af[i] = *(const bf16x8*)(As + (wm + i * 16 + l16) * 32 + quad * 8);
#pragma unroll
    for (int j = 0; j < 4; ++j)
      bfr[j] = *(const bf16x8*)(Bs + (wn + j * 16 + l16) * 32 + quad * 8);
#pragma unroll
    for (int i = 0; i < 4; ++i)
#pragma unroll
      for (int j = 0; j < 4; ++j)
        acc[i][j] = __builtin_amdgcn_mfma_f32_16x16x32_bf16(af[i], bfr[j], acc[i][j], 0, 0, 0);
  }
#pragma unroll
  for (int i = 0; i < 4; ++i)
#pragma unroll
    for (int j = 0; j < 4; ++j)
#pragma unroll
      for (int r = 0; r < 4; ++r) {
        int gm = bm + wm + i * 16 + quad * 4 + r;
        int gn = bn + wn + j * 16 + l16;
        if (gm < D.M && gn < D.N) D.C[(size_t)gm * D.ldc + gn] = (bf16_t)acc[i][j][r];
      }
}

// ---------------------------------------------------------------- fused pack + rope
__global__ void pack_qk_k(const bf16_t* __restrict__ qcat, const bf16_t* __restrict__ khead,
                          const bf16_t* __restrict__ xa,
                          const bf16_t* __restrict__ fc, const bf16_t* __restrict__ fs,
                          bf16_t* __restrict__ Qp, bf16_t* __restrict__ Kp) {
  int idx = blockIdx.x * blockDim.x + threadIdx.x;
  if (idx >= NH * T_DIM * 96) return;
  int j = idx % 96;
  int t = (idx / 96) % T_DIM;
  int h = idx / (96 * T_DIM);
  if (blockIdx.y == 0) {
    const float scale = 0.07216878364870323f;  // 1/sqrt(HS+DHR)
    bf16_t* out = Qp + ((size_t)h * T_DIM + t) * QKD;
    if (j < 64) {
      float a = (float)qcat[(size_t)t * 3072 + h * HS + 2 * j];
      float b = (float)qcat[(size_t)t * 3072 + h * HS + 2 * j + 1];
      out[2 * j] = (bf16_t)(a * scale);
      out[2 * j + 1] = (bf16_t)(b * scale);
    } else {
      int i = j - 64;
      float re = (float)qcat[(size_t)t * 3072 + 2048 + h * DHR + 2 * i];
      float im = (float)qcat[(size_t)t * 3072 + 2048 + h * DHR + 2 * i + 1];
      float c = (float)fc[t * 32 + i], s = (float)fs[t * 32 + i];
      out[HS + 2 * i] = (bf16_t)((re * c - im * s) * scale);
      out[HS + 2 * i + 1] = (bf16_t)((re * s + im * c) * scale);
    }
  } else {
    bf16_t* out = Kp + ((size_t)h * T_DIM + t) * QKD;
    if (j < 64) {
      out[2 * j] = khead[(size_t)t * C_DIM + h * HS + 2 * j];
      out[2 * j + 1] = khead[(size_t)t * C_DIM + h * HS + 2 * j + 1];
    } else {
      int i = j - 64;
      float re = (float)xa[(size_t)t * 2112 + 2048 + 2 * i];
      float im = (float)xa[(size_t)t * 2112 + 2048 + 2 * i + 1];
      float c = (float)fc[t * 32 + i], s = (float)fs[t * 32 + i];
      out[HS + 2 * i] = (bf16_t)(re * c - im * s);
      out[HS + 2 * i + 1] = (bf16_t)(re * s + im * c);
    }
  }
}

// ---------------------------------------------------------------- flash attention
// S^T orientation (rows=s, cols=t), 4 waves x 32 t-rows, FBM=128, FBN=64, KV-split.
// blockIdx.x = p in [0,24): p<16: qt=8+(p>>1), chunk=p&1, partial; p>=16: qt=23-p, full.
#define FBM 128
#define FBN 64
#define KPITCH 200
#define VPITCH 72
#define PPITCH 72

__global__ __launch_bounds__(256) void flash_k(const bf16_t* __restrict__ Qp,
                                               const bf16_t* __restrict__ Kp,
                                               const bf16_t* __restrict__ VT,
                                               void* __restrict__ Y,
                                               const int* __restrict__ flag,
                                               float* __restrict__ Opart,
                                               float* __restrict__ Mpart,
                                               float* __restrict__ Lpart) {
  __shared__ bf16_t Ksm[FBN * KPITCH];    // 25.6 KB
  __shared__ bf16_t Vtsm[HS * VPITCH];    // 18.4 KB
  __shared__ bf16_t Psm[4][32 * PPITCH];  // 18.4 KB
  const int tid = threadIdx.x;
  const int lane = tid & 63, wave = tid >> 6;  // wave 0..3, 32 t-rows each
  const int l16 = lane & 15, quad = lane >> 4;
  const int h = blockIdx.y;
  const int p = blockIdx.x;
  int qt, kt0, kt1, partial;
  if (p < 16) {
    qt = 8 + (p >> 1);
    int half = qt + 1;
    kt0 = (p & 1) ? half : 0;
    kt1 = (p & 1) ? (2 * qt + 2) : half;
    partial = 1;
  } else {
    qt = 23 - p; kt0 = 0; kt1 = 2 * qt + 2; partial = 0;
  }
  const int qb = qt * FBM;
  const int f32out = *flag;

  // Q fragments: two 16-row t-tiles per wave (B-operand: n=l16 rows)
  bf16x8 aq[2][6];
#pragma unroll
  for (int tt = 0; tt < 2; ++tt) {
    const bf16_t* qbase = Qp + ((size_t)h * T_DIM + qb + wave * 32 + tt * 16 + l16) * QKD;
#pragma unroll
    for (int c = 0; c < 6; ++c) aq[tt][c] = *(const bf16x8*)(qbase + c * 32 + quad * 8);
  }

  f32x4 o[2][8] = {};           // O^T: rows d (8 tiles), cols t (l16); [tt]
  float m_i[2] = {-3.0e38f, -3.0e38f}, l_i[2] = {0.f, 0.f};

  const bf16_t* kg_base = Kp + (size_t)h * T_DIM * QKD;
  const bf16_t* vg_base = VT + (size_t)(h * HS) * T_DIM;

  // register prefetch (6 K-chunks + 4 V-chunks per thread, 256 threads)
  bf16x8 kreg[6], vreg[4];
  {
    const bf16_t* kg = kg_base + (size_t)kt0 * FBN * QKD;
#pragma unroll
    for (int i = 0; i < 6; ++i) {
      int idx = i * 256 + tid;  // 64 rows * 24 vec8
      kreg[i] = *(const bf16x8*)(kg + (size_t)idx * 8);
    }
    const bf16_t* vg = vg_base + kt0 * FBN;
#pragma unroll
    for (int i = 0; i < 4; ++i) {
      int idx = i * 256 + tid, row = idx >> 3, c8 = idx & 7;
      vreg[i] = *(const bf16x8*)(vg + (size_t)row * T_DIM + c8 * 8);
    }
  }

  for (int kt = kt0; kt < kt1; ++kt) {
    __syncthreads();  // previous compute done -> LDS writable
#pragma unroll
    for (int i = 0; i < 6; ++i) {
      int idx = i * 256 + tid, row = idx / 24, c8 = idx % 24;
      *(bf16x8*)(Ksm + row * KPITCH + c8 * 8) = kreg[i];
    }
#pragma unroll
    for (int i = 0; i < 4; ++i) {
      int idx = i * 256 + tid, row = idx >> 3, c8 = idx & 7;
      *(bf16x8*)(Vtsm + row * VPITCH + c8 * 8) = vreg[i];
    }
    __syncthreads();  // LDS ready
    if (kt + 1 < kt1) {
      const bf16_t* kg = kg_base + (size_t)(kt + 1) * FBN * QKD;
#pragma unroll
      for (int i = 0; i < 6; ++i) {
        int idx = i * 256 + tid;
        kreg[i] = *(const bf16x8*)(kg + (size_t)idx * 8);
      }
      const bf16_t* vg = vg_base + (kt + 1) * FBN;
#pragma unroll
      for (int i = 0; i < 4; ++i) {
        int idx = i * 256 + tid, row = idx >> 3, c8 = idx & 7;
        vreg[i] = *(const bf16x8*)(vg + (size_t)row * T_DIM + c8 * 8);
      }
    }
    // S^T = K @ Q^T : rows s (4 tiles of 16), cols t (2 tiles, l16). Each K-frag feeds 2 MFMAs.
    f32x4 sc[2][4] = {};
#pragma unroll
    for (int nt = 0; nt < 4; ++nt)
#pragma unroll
      for (int c = 0; c < 6; ++c) {
        bf16x8 bk = *(const bf16x8*)(Ksm + (nt * 16 + l16) * KPITCH + c * 32 + quad * 8);
        sc[0][nt] = __builtin_amdgcn_mfma_f32_16x16x32_bf16(bk, aq[0][c], sc[0][nt], 0, 0, 0);
        sc[1][nt] = __builtin_amdgcn_mfma_f32_16x16x32_bf16(bk, aq[1][c], sc[1][nt], 0, 0, 0);
      }
    if (kt >= 2 * qt) {  // diagonal region
#pragma unroll
      for (int tt = 0; tt < 2; ++tt) {
        int t_glob = qb + wave * 32 + tt * 16 + l16;
#pragma unroll
        for (int nt = 0; nt < 4; ++nt) {
          int s_base = kt * FBN + nt * 16 + quad * 4;
#pragma unroll
          for (int r = 0; r < 4; ++r)
            if (s_base + r > t_glob) sc[tt][nt][r] = -3.0e38f;
        }
      }
    }
    // online softmax: per t-column (l16); reduce in-register over nt,r then 2 shfl over quads
#pragma unroll
    for (int tt = 0; tt < 2; ++tt) {
      float mx = sc[tt][0][0];
#pragma unroll
      for (int nt = 0; nt < 4; ++nt)
#pragma unroll
        for (int r = 0; r < 4; ++r) mx = fmaxf(mx, sc[tt][nt][r]);
      mx = fmaxf(mx, __shfl_xor(mx, 16, 64));
      mx = fmaxf(mx, __shfl_xor(mx, 32, 64));
      float mn = fmaxf(m_i[tt], mx);
      float alpha = exp2f((m_i[tt] - mn) * 1.4426950408889634f);
      float rs = 0.f;
#pragma unroll
      for (int nt = 0; nt < 4; ++nt) {
        bf16x4 pk;
#pragma unroll
        for (int r = 0; r < 4; ++r) {
          float pv = exp2f((sc[tt][nt][r] - mn) * 1.4426950408889634f);
          rs += pv;
          pk[r] = (bf16_t)pv;
        }
        *(bf16x4*)(&Psm[wave][(tt * 16 + l16) * PPITCH + nt * 16 + quad * 4]) = pk;
      }
      rs += __shfl_xor(rs, 16, 64);
      rs += __shfl_xor(rs, 32, 64);
      l_i[tt] = l_i[tt] * alpha + rs;
      m_i[tt] = mn;
#pragma unroll
      for (int dt = 0; dt < 8; ++dt) o[tt][dt] *= alpha;
    }
    // O^T += V^T @ P^T : each V-frag feeds 2 MFMAs (per-wave Psm, no extra barrier)
#pragma unroll
    for (int s2 = 0; s2 < 2; ++s2) {
      bf16x8 ap0 = *(const bf16x8*)(&Psm[wave][l16 * PPITCH + s2 * 32 + quad * 8]);
      bf16x8 ap1 = *(const bf16x8*)(&Psm[wave][(16 + l16) * PPITCH + s2 * 32 + quad * 8]);
#pragma unroll
      for (int dt = 0; dt < 8; ++dt) {
        bf16x8 bv = *(const bf16x8*)(Vtsm + (dt * 16 + l16) * VPITCH + s2 * 32 + quad * 8);
        o[0][dt] = __builtin_amdgcn_mfma_f32_16x16x32_bf16(bv, ap0, o[0][dt], 0, 0, 0);
        o[1][dt] = __builtin_amdgcn_mfma_f32_16x16x32_bf16(bv, ap1, o[1][dt], 0, 0, 0);
      }
    }
  }

  if (!partial) {
#pragma unroll
    for (int tt = 0; tt < 2; ++tt) {
      float inv = 1.0f / l_i[tt];
      int t = qb + wave * 32 + tt * 16 + l16;
#pragma unroll
      for (int dt = 0; dt < 8; ++dt) {
        size_t oi = (size_t)t * C_DIM + h * HS + dt * 16 + quad * 4;
        if (f32out) {
          f32x4 v;
#pragma unroll
          for (int r = 0; r < 4; ++r) v[r] = o[tt][dt][r] * inv;
          *(f32x4*)((float*)Y + oi) = v;
        } else {
          bf16x4 v;
#pragma unroll
          for (int r = 0; r < 4; ++r) v[r] = (bf16_t)(o[tt][dt][r] * inv);
          *(bf16x4*)((bf16_t*)Y + oi) = v;
        }
      }
    }
  } else {
    const int pi = h * 16 + p;  // p < 16
#pragma unroll
    for (int tt = 0; tt < 2; ++tt) {
      int rowl = wave * 32 + tt * 16 + l16;  // 0..127
      float* ob = Opart + ((size_t)pi * 128 + rowl) * 128;
#pragma unroll
      for (int dt = 0; dt < 8; ++dt) {
        f32x4 v = o[tt][dt];
        *(f32x4*)(ob + dt * 16 + quad * 4) = v;
      }
      if (quad == 0) {
        Mpart[(size_t)pi * 128 + rowl] = m_i[tt];
        Lpart[(size_t)pi * 128 + rowl] = l_i[tt];
      }
    }
  }
}

// ---------------------------------------------------------------- combine partials (qt>=8)
__global__ __launch_bounds__(256) void combine_k(const float* __restrict__ Opart,
                                                 const float* __restrict__ Mpart,
                                                 const float* __restrict__ Lpart,
                                                 void* __restrict__ Y,
                                                 const int* __restrict__ flag) {
  const int h = blockIdx.y;
  const int qi = blockIdx.x;           // 0..7 -> qt = 8+qi
  const int pi0 = h * 16 + qi * 2, pi1 = pi0 + 1;
  const int row = threadIdx.x >> 1;    // 0..127
  const int c0 = (threadIdx.x & 1) * 64;
  const int f32out = *flag;
  float m0 = Mpart[(size_t)pi0 * 128 + row], m1 = Mpart[(size_t)pi1 * 128 + row];
  float l0 = Lpart[(size_t)pi0 * 128 + row], l1 = Lpart[(size_t)pi1 * 128 + row];
  float ms = fmaxf(m0, m1);
  float w0 = exp2f((m0 - ms) * 1.4426950408889634f);
  float w1 = exp2f((m1 - ms) * 1.4426950408889634f);
  float inv = 1.0f / (l0 * w0 + l1 * w1);
  const float* O0 = Opart + ((size_t)pi0 * 128 + row) * 128 + c0;
  const float* O1 = Opart + ((size_t)pi1 * 128 + row) * 128 + c0;
  int t = (8 + qi) * 128 + row;
  size_t ob = (size_t)t * C_DIM + h * HS + c0;
#pragma unroll
  for (int d4 = 0; d4 < 64; d4 += 4) {
    f32x4 a = *(const f32x4*)(O0 + d4);
    f32x4 b = *(const f32x4*)(O1 + d4);
#pragma unroll
    for (int j = 0; j < 4; ++j) {
      float v = (a[j] * w0 + b[j] * w1) * inv;
      if (f32out) ((float*)Y)[ob + d4 + j] = v;
      else        ((bf16_t*)Y)[ob + d4 + j] = (bf16_t)v;
    }
  }
}

// ---------------------------------------------------------------- launch
extern "C" void kernel_launch(void* const* d_in, const int* in_sizes, int n_in,
                              void* d_out, int out_size, void* d_ws, size_t ws_size,
                              hipStream_t stream) {
  bf16_t* w = (bf16_t*)d_ws;
  int* flag = (int*)d_ws;  // first 4 bytes; buffers start at element 64

  if (ws_size < (size_t)34472000 * 2 + 128) return;

  // ---- workspace layout (bf16 elements), lifetime-aliased ----
  bf16_t* fcc    = w + 64;        // 65536
  bf16_t* fsc    = w + 65600;     // 65536
  bf16_t* xc     = w + 131136;    // 4194304
  bf16_t* BigB   = w + 4325440;   // 4325376 = [W_dq(1536) | W_dkv(512) | W_kr(64)] x 2048
  bf16_t* dqc    = BigB;
  bf16_t* dkvc   = BigB + 3145728;
  bf16_t* krc    = BigB + 4194304;
  bf16_t* Bq     = w + 8650816;   // 4718592 = [W_uq_t(2048) | W_qr(1024)] x 1536
  bf16_t* W_uq_t = Bq;
  bf16_t* qrc    = Bq + 3145728;
  bf16_t* xa     = w + 13369408;  // 4325376: cols [c_q(1536) | c_kv(512) | k_r(64)], ld 2112
  bf16_t* qcat   = w + 17694784;  // 6291456: cols [q_up(2048) | q_r(1024)], ld 3072
  bf16_t* k_head = w + 23986240;  // 4194304
  bf16_t* vhatT  = w + 28180544;  // 4194304
  bf16_t* ukc    = w + 32374848;  // 1048576
  bf16_t* Pt     = w + 33423424;  // 1048576
  // aliases (lifetime-disjoint, verified by launch order below)
  bf16_t* woc    = qcat;          // W_o bf16; dead before qcat GEMM writes here
  bf16_t* W_uv_t = k_head;        // dead before k_head GEMM writes here
  bf16_t* Qpack  = xc;            // xc+BigB dead after xa GEMM
  bf16_t* Kpack  = qcat;          // qcat dead after pack
  // flash partials (f32) over Bq+xa region (dead once pack is done)
  float* Opart = (float*)(w + 6422592);   // 256*128*128 f32 = 16.8 MB -> ends elem 14811200
  float* Mpart = (float*)(w + 14811200);  // 32768 f32
  float* Lpart = (float*)(w + 14876736);  // 32768 f32 -> ends 14942272 < 17694784 (Kpack) OK

  detect_k<<<1, 64, 0, stream>>>((const bf16_t*)d_in[0], flag);

  CvPack cp;
  const void* srcs[9] = {d_in[1], d_in[2], d_in[0], d_in[3], d_in[5], d_in[9], d_in[8], d_in[6], d_in[10]};
  bf16_t* dsts[9]     = {fcc,     fsc,     xc,      dqc,     dkvc,    krc,     qrc,     ukc,     woc};
  int ns[9] = {T_DIM * 32, T_DIM * 32, T_DIM * C_DIM, NLQ * C_DIM, NLKV * C_DIM,
               DHR * C_DIM, NH * DHR * NLQ, C_DIM * NLKV, C_DIM * C_DIM};
  for (int i = 0; i < 9; ++i) { cp.src[i] = srcs[i]; cp.dst[i] = dsts[i]; cp.n[i] = ns[i]; }
  convert_all_k<<<dim3(512, 9), 256, 0, stream>>>(cp, flag);

  dim3 tb(32, 8);
  transpose_k<<<dim3(64, 48), tb, 0, stream>>>(d_in[4], W_uq_t, 1536, 2048, flag);
  transpose_k<<<dim3(16, 64), tb, 0, stream>>>(d_in[7], W_uv_t, 2048, 512, flag);

  // G1: xa = x @ [W_dq;W_dkv;W_kr]^T (272 blk)  ||  Pt = W_o @ W_uv (64 blk)
  {
    GGrp g;
    g.d[0] = {xc,  BigB,   xa, 2048, 2112, 2048, 2048, 2048, 2112, 16, 0};
    g.d[1] = {woc, W_uv_t, Pt, 2048,  512, 2048, 2048, 2048,  512, 16, 272};
    gemm_group<<<336, 256, 0, stream>>>(g, 2);
  }
  // G2: qcat (384 blk) || k_head (256 blk) || vhatT (256 blk)
  {
    GGrp g;
    g.d[0] = {xa,        Bq,        qcat,   2048, 3072, 1536, 2112, 1536, 3072, 16, 0};
    g.d[1] = {xa + 1536, ukc,       k_head, 2048, 2048,  512, 2112,  512, 2048, 16, 384};
    g.d[2] = {Pt,        xa + 1536, vhatT,  2048, 2048,  512,  512, 2112, 2048, 16, 640};
    gemm_group<<<896, 256, 0, stream>>>(g, 3);
  }

  int pk = (NH * T_DIM * 96 + 255) / 256;
  pack_qk_k<<<dim3(pk, 2), 256, 0, stream>>>(qcat, k_head, xa, fcc, fsc, Qpack, Kpack);

  flash_k<<<dim3(24, NH), 256, 0, stream>>>(Qpack, Kpack, vhatT, d_out, flag, Opart, Mpart, Lpart);
  combine_k<<<dim3(8, NH), 256, 0, stream>>>(Opart, Mpart, Lpart, d_out, flag);
}

// Round 8
// 351.540 us; speedup vs baseline: 1.2614x; 1.0360x over previous
//
#include <hip/hip_runtime.h>
#include <hip/hip_bf16.h>
#include <math.h>

typedef __bf16 bf16_t;
typedef __bf16 bf16x4 __attribute__((ext_vector_type(4)));
typedef __bf16 bf16x8 __attribute__((ext_vector_type(8)));
typedef float f32x4 __attribute__((ext_vector_type(4)));

#define T_DIM 2048
#define C_DIM 2048
#define NH 16
#define HS 128
#define NLQ 1536
#define NLKV 512
#define DHR 64
#define QKD 192  // HS + DHR

// inline dtype probe: true (f32 inputs) iff reading x as bf16 yields huge/NaN.
__device__ __forceinline__ int probe_f32(const bf16_t* __restrict__ x) {
  int lane = threadIdx.x & 63;
  int bad = 0;
#pragma unroll
  for (int i = 0; i < 4; ++i) {
    float v = (float)x[lane + i * 64];
    if (!(fabsf(v) < 1.0e6f)) bad = 1;
  }
  return (__ballot(bad) != 0ull) ? 1 : 0;
}

// ---------------------------------------------------------------- prep: 9 converts + 2 transposes
struct PrepPack {
  const void* src[9];
  bf16_t* dst[9];
  int n[9];
  const void* tsrc[2];
  bf16_t* tdst[2];
  int tR[2], tC[2], tbx[2];  // in R x C -> out C x R; tbx = C/32
};

__global__ __launch_bounds__(256) void prep_k(PrepPack p, const bf16_t* __restrict__ xprobe) {
  __shared__ bf16_t tile[32][33];
  const int f32 = probe_f32(xprobe);
  const int which = blockIdx.y;
  if (which < 9) {
    const int n = p.n[which];
    const int stride = gridDim.x * 256 * 8;
    for (int i = (blockIdx.x * 256 + threadIdx.x) * 8; i < n; i += stride) {
      if (f32) {
        const float* s = (const float*)p.src[which] + i;
        f32x4 lo = *(const f32x4*)s;
        f32x4 hi = *(const f32x4*)(s + 4);
        bf16x8 v;
#pragma unroll
        for (int j = 0; j < 4; ++j) { v[j] = (bf16_t)lo[j]; v[j + 4] = (bf16_t)hi[j]; }
        *(bf16x8*)(p.dst[which] + i) = v;
      } else {
        *(bf16x8*)(p.dst[which] + i) = *(const bf16x8*)((const bf16_t*)p.src[which] + i);
      }
    }
  } else {
    const int ts = which - 9;
    const int R = p.tR[ts], C = p.tC[ts], tbx = p.tbx[ts];
    const int ntiles = tbx * (R / 32);
    if ((int)blockIdx.x >= ntiles) return;
    const void* in = p.tsrc[ts];
    bf16_t* out = p.tdst[ts];
    int bx = (blockIdx.x % tbx) * 32, by = (blockIdx.x / tbx) * 32;
    int tx = threadIdx.x & 31, ty = threadIdx.x >> 5;  // 32 x 8
    for (int i = ty; i < 32; i += 8) {
      int r = by + i, c = bx + tx;
      size_t idx = (size_t)r * C + c;
      tile[i][tx] = f32 ? (bf16_t)((const float*)in)[idx] : ((const bf16_t*)in)[idx];
    }
    __syncthreads();
    for (int i = ty; i < 32; i += 8) {
      int r = bx + i, c = by + tx;  // out[r][c] = in[c][r]
      out[(size_t)r * R + c] = tile[tx][i];
    }
  }
}

// ---------------------------------------------------------------- async global->LDS (16B)
__device__ __forceinline__ void async16(const bf16_t* g, bf16_t* l) {
  __builtin_amdgcn_global_load_lds(
      (const __attribute__((address_space(1))) void*)g,
      (__attribute__((address_space(3))) void*)l, 16, 0, 0);
}

// ---------------------------------------------------------------- grouped GEMM  C = A @ B^T
#define BM 128
#define BN 128

struct GDesc {
  const bf16_t* A; const bf16_t* B; bf16_t* C;
  int M, N, K, lda, ldb, ldc, mb, bx0;
};
struct GGrp { GDesc d[3]; };

__global__ __launch_bounds__(256) void gemm_group(GGrp g, int nseg) {
  int bx = blockIdx.x;
  int s = 0;
  while (s + 1 < nseg && bx >= g.d[s + 1].bx0) ++s;
  const GDesc D = g.d[s];
  const int local = bx - D.bx0;
  const int bm = (local % D.mb) * BM, bn = (local / D.mb) * BN;

  __shared__ bf16_t As[BM * 32];  // 8 KB
  __shared__ bf16_t Bs[BN * 32];  // 8 KB
  const int tid = threadIdx.x;
  const int lane = tid & 63;
  const int wave = tid >> 6;
  const int l16 = lane & 15, quad = lane >> 4;
  const int wm = (wave >> 1) * 64, wn = (wave & 1) * 64;
  const int srow = lane >> 2;
  const int scol = (lane & 3) * 8;
  f32x4 acc[4][4] = {};

  for (int k0 = 0; k0 < D.K; k0 += 32) {
    __syncthreads();
#pragma unroll
    for (int pss = 0; pss < 2; ++pss) {
      int rowT = pss * 64 + wave * 16 + srow;
      int ar = bm + rowT; if (ar > D.M - 1) ar = D.M - 1;
      async16(D.A + (size_t)ar * D.lda + k0 + scol, As + (pss * 64 + wave * 16) * 32);
      int br = bn + rowT; if (br > D.N - 1) br = D.N - 1;
      async16(D.B + (size_t)br * D.ldb + k0 + scol, Bs + (pss * 64 + wave * 16) * 32);
    }
    __syncthreads();
    bf16x8 af[4], bfr[4];
#pragma unroll
    for (int i = 0; i < 4; ++i)
      af[i] = *(const bf16x8*)(As + (wm + i * 16 + l16) * 32 + quad * 8);
#pragma unroll
    for (int j = 0; j < 4; ++j)
      bfr[j] = *(const bf16x8*)(Bs + (wn + j * 16 + l16) * 32 + quad * 8);
#pragma unroll
    for (int i = 0; i < 4; ++i)
#pragma unroll
      for (int j = 0; j < 4; ++j)
        acc[i][j] = __builtin_amdgcn_mfma_f32_16x16x32_bf16(af[i], bfr[j], acc[i][j], 0, 0, 0);
  }
#pragma unroll
  for (int i = 0; i < 4; ++i)
#pragma unroll
    for (int j = 0; j < 4; ++j)
#pragma unroll
      for (int r = 0; r < 4; ++r) {
        int gm = bm + wm + i * 16 + quad * 4 + r;
        int gn = bn + wn + j * 16 + l16;
        if (gm < D.M && gn < D.N) D.C[(size_t)gm * D.ldc + gn] = (bf16_t)acc[i][j][r];
      }
}

// ---------------------------------------------------------------- fused pack + rope
__global__ void pack_qk_k(const bf16_t* __restrict__ qcat, const bf16_t* __restrict__ khead,
                          const bf16_t* __restrict__ xa,
                          const bf16_t* __restrict__ fc, const bf16_t* __restrict__ fs,
                          bf16_t* __restrict__ Qp, bf16_t* __restrict__ Kp) {
  int idx = blockIdx.x * blockDim.x + threadIdx.x;
  if (idx >= NH * T_DIM * 96) return;
  int j = idx % 96;
  int t = (idx / 96) % T_DIM;
  int h = idx / (96 * T_DIM);
  if (blockIdx.y == 0) {
    const float scale = 0.07216878364870323f;  // 1/sqrt(HS+DHR)
    bf16_t* out = Qp + ((size_t)h * T_DIM + t) * QKD;
    if (j < 64) {
      float a = (float)qcat[(size_t)t * 3072 + h * HS + 2 * j];
      float b = (float)qcat[(size_t)t * 3072 + h * HS + 2 * j + 1];
      out[2 * j] = (bf16_t)(a * scale);
      out[2 * j + 1] = (bf16_t)(b * scale);
    } else {
      int i = j - 64;
      float re = (float)qcat[(size_t)t * 3072 + 2048 + h * DHR + 2 * i];
      float im = (float)qcat[(size_t)t * 3072 + 2048 + h * DHR + 2 * i + 1];
      float c = (float)fc[t * 32 + i], s = (float)fs[t * 32 + i];
      out[HS + 2 * i] = (bf16_t)((re * c - im * s) * scale);
      out[HS + 2 * i + 1] = (bf16_t)((re * s + im * c) * scale);
    }
  } else {
    bf16_t* out = Kp + ((size_t)h * T_DIM + t) * QKD;
    if (j < 64) {
      out[2 * j] = khead[(size_t)t * C_DIM + h * HS + 2 * j];
      out[2 * j + 1] = khead[(size_t)t * C_DIM + h * HS + 2 * j + 1];
    } else {
      int i = j - 64;
      float re = (float)xa[(size_t)t * 2112 + 2048 + 2 * i];
      float im = (float)xa[(size_t)t * 2112 + 2048 + 2 * i + 1];
      float c = (float)fc[t * 32 + i], s = (float)fs[t * 32 + i];
      out[HS + 2 * i] = (bf16_t)(re * c - im * s);
      out[HS + 2 * i + 1] = (bf16_t)(re * s + im * c);
    }
  }
}

// ---------------------------------------------------------------- flash attention
// S^T orientation, 4 waves x 32 t-rows, FBM=128, FBN=64, KV-split,
// XCD-pinned block id: id = xcd + 8*slot; h = xcd + 8*(slot/24); p = slot%24.
#define FBM 128
#define FBN 64
#define KPITCH 200
#define VPITCH 72
#define PPITCH 72

__global__ __launch_bounds__(256) void flash_k(const bf16_t* __restrict__ Qp,
                                               const bf16_t* __restrict__ Kp,
                                               const bf16_t* __restrict__ VT,
                                               void* __restrict__ Y,
                                               const bf16_t* __restrict__ xprobe,
                                               float* __restrict__ Opart,
                                               float* __restrict__ Mpart,
                                               float* __restrict__ Lpart) {
  __shared__ bf16_t Ksm[FBN * KPITCH];    // 25.6 KB
  __shared__ bf16_t Vtsm[HS * VPITCH];    // 18.4 KB
  __shared__ bf16_t Psm[4][32 * PPITCH];  // 18.4 KB
  const int tid = threadIdx.x;
  const int lane = tid & 63, wave = tid >> 6;  // wave 0..3, 32 t-rows each
  const int l16 = lane & 15, quad = lane >> 4;
  const int id = blockIdx.x;
  const int xcd = id & 7, slot = id >> 3;
  const int h = xcd + 8 * (slot / 24);
  const int p = slot % 24;
  int qt, kt0, kt1, partial;
  if (p < 16) {
    qt = 8 + (p >> 1);
    int half = qt + 1;
    kt0 = (p & 1) ? half : 0;
    kt1 = (p & 1) ? (2 * qt + 2) : half;
    partial = 1;
  } else {
    qt = 23 - p; kt0 = 0; kt1 = 2 * qt + 2; partial = 0;
  }
  const int qb = qt * FBM;
  const int f32out = probe_f32(xprobe);

  // Q fragments: two 16-row t-tiles per wave (B-operand: n=l16 rows)
  bf16x8 aq[2][6];
#pragma unroll
  for (int tt = 0; tt < 2; ++tt) {
    const bf16_t* qbase = Qp + ((size_t)h * T_DIM + qb + wave * 32 + tt * 16 + l16) * QKD;
#pragma unroll
    for (int c = 0; c < 6; ++c) aq[tt][c] = *(const bf16x8*)(qbase + c * 32 + quad * 8);
  }

  f32x4 o[2][8] = {};           // O^T: rows d (8 tiles), cols t (l16); [tt]
  float m_i[2] = {-3.0e38f, -3.0e38f}, l_i[2] = {0.f, 0.f};

  const bf16_t* kg_base = Kp + (size_t)h * T_DIM * QKD;
  const bf16_t* vg_base = VT + (size_t)(h * HS) * T_DIM;

  // register prefetch (6 K-chunks + 4 V-chunks per thread, 256 threads)
  bf16x8 kreg[6], vreg[4];
  {
    const bf16_t* kg = kg_base + (size_t)kt0 * FBN * QKD;
#pragma unroll
    for (int i = 0; i < 6; ++i) {
      int idx = i * 256 + tid;  // 64 rows * 24 vec8
      kreg[i] = *(const bf16x8*)(kg + (size_t)idx * 8);
    }
    const bf16_t* vg = vg_base + kt0 * FBN;
#pragma unroll
    for (int i = 0; i < 4; ++i) {
      int idx = i * 256 + tid, row = idx >> 3, c8 = idx & 7;
      vreg[i] = *(const bf16x8*)(vg + (size_t)row * T_DIM + c8 * 8);
    }
  }

  for (int kt = kt0; kt < kt1; ++kt) {
    __syncthreads();  // previous compute done -> LDS writable
#pragma unroll
    for (int i = 0; i < 6; ++i) {
      int idx = i * 256 + tid, row = idx / 24, c8 = idx % 24;
      *(bf16x8*)(Ksm + row * KPITCH + c8 * 8) = kreg[i];
    }
#pragma unroll
    for (int i = 0; i < 4; ++i) {
      int idx = i * 256 + tid, row = idx >> 3, c8 = idx & 7;
      *(bf16x8*)(Vtsm + row * VPITCH + c8 * 8) = vreg[i];
    }
    __syncthreads();  // LDS ready
    if (kt + 1 < kt1) {
      const bf16_t* kg = kg_base + (size_t)(kt + 1) * FBN * QKD;
#pragma unroll
      for (int i = 0; i < 6; ++i) {
        int idx = i * 256 + tid;
        kreg[i] = *(const bf16x8*)(kg + (size_t)idx * 8);
      }
      const bf16_t* vg = vg_base + (kt + 1) * FBN;
#pragma unroll
      for (int i = 0; i < 4; ++i) {
        int idx = i * 256 + tid, row = idx >> 3, c8 = idx & 7;
        vreg[i] = *(const bf16x8*)(vg + (size_t)row * T_DIM + c8 * 8);
      }
    }
    // S^T = K @ Q^T : rows s (4 tiles of 16), cols t (2 tiles, l16)
    f32x4 sc[2][4] = {};
#pragma unroll
    for (int nt = 0; nt < 4; ++nt)
#pragma unroll
      for (int c = 0; c < 6; ++c) {
        bf16x8 bk = *(const bf16x8*)(Ksm + (nt * 16 + l16) * KPITCH + c * 32 + quad * 8);
        sc[0][nt] = __builtin_amdgcn_mfma_f32_16x16x32_bf16(bk, aq[0][c], sc[0][nt], 0, 0, 0);
        sc[1][nt] = __builtin_amdgcn_mfma_f32_16x16x32_bf16(bk, aq[1][c], sc[1][nt], 0, 0, 0);
      }
    if (kt >= 2 * qt) {  // diagonal region
#pragma unroll
      for (int tt = 0; tt < 2; ++tt) {
        int t_glob = qb + wave * 32 + tt * 16 + l16;
#pragma unroll
        for (int nt = 0; nt < 4; ++nt) {
          int s_base = kt * FBN + nt * 16 + quad * 4;
#pragma unroll
          for (int r = 0; r < 4; ++r)
            if (s_base + r > t_glob) sc[tt][nt][r] = -3.0e38f;
        }
      }
    }
    // online softmax: per t-column (l16); in-register reduce + 2 shfl over quads
#pragma unroll
    for (int tt = 0; tt < 2; ++tt) {
      float mx = sc[tt][0][0];
#pragma unroll
      for (int nt = 0; nt < 4; ++nt)
#pragma unroll
        for (int r = 0; r < 4; ++r) mx = fmaxf(mx, sc[tt][nt][r]);
      mx = fmaxf(mx, __shfl_xor(mx, 16, 64));
      mx = fmaxf(mx, __shfl_xor(mx, 32, 64));
      float mn = fmaxf(m_i[tt], mx);
      float alpha = exp2f((m_i[tt] - mn) * 1.4426950408889634f);
      float rs = 0.f;
#pragma unroll
      for (int nt = 0; nt < 4; ++nt) {
        bf16x4 pk;
#pragma unroll
        for (int r = 0; r < 4; ++r) {
          float pv = exp2f((sc[tt][nt][r] - mn) * 1.4426950408889634f);
          rs += pv;
          pk[r] = (bf16_t)pv;
        }
        *(bf16x4*)(&Psm[wave][(tt * 16 + l16) * PPITCH + nt * 16 + quad * 4]) = pk;
      }
      rs += __shfl_xor(rs, 16, 64);
      rs += __shfl_xor(rs, 32, 64);
      l_i[tt] = l_i[tt] * alpha + rs;
      m_i[tt] = mn;
#pragma unroll
      for (int dt = 0; dt < 8; ++dt) o[tt][dt] *= alpha;
    }
    // O^T += V^T @ P^T (per-wave Psm, no extra barrier)
#pragma unroll
    for (int s2 = 0; s2 < 2; ++s2) {
      bf16x8 ap0 = *(const bf16x8*)(&Psm[wave][l16 * PPITCH + s2 * 32 + quad * 8]);
      bf16x8 ap1 = *(const bf16x8*)(&Psm[wave][(16 + l16) * PPITCH + s2 * 32 + quad * 8]);
#pragma unroll
      for (int dt = 0; dt < 8; ++dt) {
        bf16x8 bv = *(const bf16x8*)(Vtsm + (dt * 16 + l16) * VPITCH + s2 * 32 + quad * 8);
        o[0][dt] = __builtin_amdgcn_mfma_f32_16x16x32_bf16(bv, ap0, o[0][dt], 0, 0, 0);
        o[1][dt] = __builtin_amdgcn_mfma_f32_16x16x32_bf16(bv, ap1, o[1][dt], 0, 0, 0);
      }
    }
  }

  if (!partial) {
#pragma unroll
    for (int tt = 0; tt < 2; ++tt) {
      float inv = 1.0f / l_i[tt];
      int t = qb + wave * 32 + tt * 16 + l16;
#pragma unroll
      for (int dt = 0; dt < 8; ++dt) {
        size_t oi = (size_t)t * C_DIM + h * HS + dt * 16 + quad * 4;
        if (f32out) {
          f32x4 v;
#pragma unroll
          for (int r = 0; r < 4; ++r) v[r] = o[tt][dt][r] * inv;
          *(f32x4*)((float*)Y + oi) = v;
        } else {
          bf16x4 v;
#pragma unroll
          for (int r = 0; r < 4; ++r) v[r] = (bf16_t)(o[tt][dt][r] * inv);
          *(bf16x4*)((bf16_t*)Y + oi) = v;
        }
      }
    }
  } else {
    const int pi = h * 16 + p;  // p < 16
#pragma unroll
    for (int tt = 0; tt < 2; ++tt) {
      int rowl = wave * 32 + tt * 16 + l16;  // 0..127
      float* ob = Opart + ((size_t)pi * 128 + rowl) * 128;
#pragma unroll
      for (int dt = 0; dt < 8; ++dt) {
        f32x4 v = o[tt][dt];
        *(f32x4*)(ob + dt * 16 + quad * 4) = v;
      }
      if (quad == 0) {
        Mpart[(size_t)pi * 128 + rowl] = m_i[tt];
        Lpart[(size_t)pi * 128 + rowl] = l_i[tt];
      }
    }
  }
}

// ---------------------------------------------------------------- combine partials (qt>=8)
__global__ __launch_bounds__(256) void combine_k(const float* __restrict__ Opart,
                                                 const float* __restrict__ Mpart,
                                                 const float* __restrict__ Lpart,
                                                 void* __restrict__ Y,
                                                 const bf16_t* __restrict__ xprobe) {
  const int h = blockIdx.y;
  const int qi = blockIdx.x;           // 0..7 -> qt = 8+qi
  const int pi0 = h * 16 + qi * 2, pi1 = pi0 + 1;
  const int row = threadIdx.x >> 1;    // 0..127
  const int c0 = (threadIdx.x & 1) * 64;
  const int f32out = probe_f32(xprobe);
  float m0 = Mpart[(size_t)pi0 * 128 + row], m1 = Mpart[(size_t)pi1 * 128 + row];
  float l0 = Lpart[(size_t)pi0 * 128 + row], l1 = Lpart[(size_t)pi1 * 128 + row];
  float ms = fmaxf(m0, m1);
  float w0 = exp2f((m0 - ms) * 1.4426950408889634f);
  float w1 = exp2f((m1 - ms) * 1.4426950408889634f);
  float inv = 1.0f / (l0 * w0 + l1 * w1);
  const float* O0 = Opart + ((size_t)pi0 * 128 + row) * 128 + c0;
  const float* O1 = Opart + ((size_t)pi1 * 128 + row) * 128 + c0;
  int t = (8 + qi) * 128 + row;
  size_t ob = (size_t)t * C_DIM + h * HS + c0;
#pragma unroll
  for (int d4 = 0; d4 < 64; d4 += 4) {
    f32x4 a = *(const f32x4*)(O0 + d4);
    f32x4 b = *(const f32x4*)(O1 + d4);
#pragma unroll
    for (int j = 0; j < 4; ++j) {
      float v = (a[j] * w0 + b[j] * w1) * inv;
      if (f32out) ((float*)Y)[ob + d4 + j] = v;
      else        ((bf16_t*)Y)[ob + d4 + j] = (bf16_t)v;
    }
  }
}

// ---------------------------------------------------------------- launch
extern "C" void kernel_launch(void* const* d_in, const int* in_sizes, int n_in,
                              void* d_out, int out_size, void* d_ws, size_t ws_size,
                              hipStream_t stream) {
  bf16_t* w = (bf16_t*)d_ws;
  const bf16_t* xprobe = (const bf16_t*)d_in[0];

  if (ws_size < (size_t)34472000 * 2 + 128) return;

  // ---- workspace layout (bf16 elements), lifetime-aliased ----
  bf16_t* fcc    = w + 64;        // 65536
  bf16_t* fsc    = w + 65600;     // 65536
  bf16_t* xc     = w + 131136;    // 4194304
  bf16_t* BigB   = w + 4325440;   // 4325376 = [W_dq(1536) | W_dkv(512) | W_kr(64)] x 2048
  bf16_t* dqc    = BigB;
  bf16_t* dkvc   = BigB + 3145728;
  bf16_t* krc    = BigB + 4194304;
  bf16_t* Bq     = w + 8650816;   // 4718592 = [W_uq_t(2048) | W_qr(1024)] x 1536
  bf16_t* W_uq_t = Bq;
  bf16_t* qrc    = Bq + 3145728;
  bf16_t* xa     = w + 13369408;  // 4325376: cols [c_q(1536) | c_kv(512) | k_r(64)], ld 2112
  bf16_t* qcat   = w + 17694784;  // 6291456: cols [q_up(2048) | q_r(1024)], ld 3072
  bf16_t* k_head = w + 23986240;  // 4194304
  bf16_t* vhatT  = w + 28180544;  // 4194304
  bf16_t* ukc    = w + 32374848;  // 1048576
  bf16_t* Pt     = w + 33423424;  // 1048576
  // aliases (lifetime-disjoint)
  bf16_t* woc    = qcat;          // dead before qcat GEMM writes here
  bf16_t* W_uv_t = k_head;        // dead before k_head GEMM writes here
  bf16_t* Qpack  = xc;            // xc+BigB dead after xa GEMM
  bf16_t* Kpack  = qcat;          // qcat dead after pack
  float* Opart = (float*)(w + 6422592);   // 16.8 MB over Bq/xa (dead after pack)
  float* Mpart = (float*)(w + 14811200);
  float* Lpart = (float*)(w + 14876736);

  // prep: 9 converts + 2 transposes, one launch
  PrepPack pp;
  const void* srcs[9] = {d_in[1], d_in[2], d_in[0], d_in[3], d_in[5], d_in[9], d_in[8], d_in[6], d_in[10]};
  bf16_t* dsts[9]     = {fcc,     fsc,     xc,      dqc,     dkvc,    krc,     qrc,     ukc,     woc};
  int ns[9] = {T_DIM * 32, T_DIM * 32, T_DIM * C_DIM, NLQ * C_DIM, NLKV * C_DIM,
               DHR * C_DIM, NH * DHR * NLQ, C_DIM * NLKV, C_DIM * C_DIM};
  for (int i = 0; i < 9; ++i) { pp.src[i] = srcs[i]; pp.dst[i] = dsts[i]; pp.n[i] = ns[i]; }
  pp.tsrc[0] = d_in[4]; pp.tdst[0] = W_uq_t; pp.tR[0] = 1536; pp.tC[0] = 2048; pp.tbx[0] = 64;
  pp.tsrc[1] = d_in[7]; pp.tdst[1] = W_uv_t; pp.tR[1] = 2048; pp.tC[1] = 512;  pp.tbx[1] = 16;
  prep_k<<<dim3(3072, 11), 256, 0, stream>>>(pp, xprobe);

  // G1: xa (272 blk) || Pt (64 blk)
  {
    GGrp g;
    g.d[0] = {xc,  BigB,   xa, 2048, 2112, 2048, 2048, 2048, 2112, 16, 0};
    g.d[1] = {woc, W_uv_t, Pt, 2048,  512, 2048, 2048, 2048,  512, 16, 272};
    gemm_group<<<336, 256, 0, stream>>>(g, 2);
  }
  // G2: qcat (384) || k_head (256) || vhatT (256)
  {
    GGrp g;
    g.d[0] = {xa,        Bq,        qcat,   2048, 3072, 1536, 2112, 1536, 3072, 16, 0};
    g.d[1] = {xa + 1536, ukc,       k_head, 2048, 2048,  512, 2112,  512, 2048, 16, 384};
    g.d[2] = {Pt,        xa + 1536, vhatT,  2048, 2048,  512,  512, 2112, 2048, 16, 640};
    gemm_group<<<896, 256, 0, stream>>>(g, 3);
  }

  int pk = (NH * T_DIM * 96 + 255) / 256;
  pack_qk_k<<<dim3(pk, 2), 256, 0, stream>>>(qcat, k_head, xa, fcc, fsc, Qpack, Kpack);

  flash_k<<<dim3(384), 256, 0, stream>>>(Qpack, Kpack, vhatT, d_out, xprobe, Opart, Mpart, Lpart);
  combine_k<<<dim3(8, NH), 256, 0, stream>>>(Opart, Mpart, Lpart, d_out, xprobe);
}